// Round 1
// baseline (560.749 us; speedup 1.0000x reference)
//
#include <hip/hip_runtime.h>
#include <hip/hip_cooperative_groups.h>

namespace cg = cooperative_groups;

#define NN 20000
#define NE 160000
#define NG 16
#define KP 1024            // padded feature dim
#define MT2 160            // max M strips of 128 in compact space
#define MPAD2 (MT2*128)    // 20480
#define NBLK 79            // ceil(20000/256)
#define PREP_GRID 640      // cooperative prep kernel grid (2.5 blocks/CU, co-resident)

typedef __attribute__((ext_vector_type(8))) short bf16x8;
typedef __attribute__((ext_vector_type(4))) float f32x4;

#define GAS __attribute__((address_space(1)))
#define LAS __attribute__((address_space(3)))

__device__ __forceinline__ unsigned short f2bf(float f) {
    unsigned int u = __float_as_uint(f);
    u += 0x7FFFu + ((u >> 16) & 1u);   // round-to-nearest-even
    return (unsigned short)(u >> 16);
}

__device__ __forceinline__ void gld_lds16(const char* g, char* l) {
    __builtin_amdgcn_global_load_lds((GAS void*)g, (LAS void*)l, 16, 0, 0);
}

// R13: the whole front end (memset + deg_cnt + partial_w2t + apply + scatter +
// axf — previously 6 serialized graph nodes) fused into ONE cooperative kernel.
// Phases separated by grid.sync(); W2 transpose runs CONCURRENTLY with the
// edge-degree atomics (independent work, split block ranges). All loops are
// block-uniform so every block executes exactly 5 grid.sync()s.
__global__ __launch_bounds__(256) void prep_kernel(
        const int* __restrict__ ei, const float* __restrict__ ew,
        const float* __restrict__ x, const float* __restrict__ W2,
        const int* __restrict__ batch, const void* __restrict__ mask,
        float* __restrict__ deg, int* __restrict__ cnt, int* __restrict__ flags,
        int* __restrict__ mtmp, float* __restrict__ dinv,
        int* __restrict__ bcnt, int* __restrict__ bmsk,
        int* __restrict__ offs, int* __restrict__ perm, int* __restrict__ bc,
        int* __restrict__ nm, int* __restrict__ cursor, float* __restrict__ out,
        int* __restrict__ ssrc, float* __restrict__ snorm,
        float* __restrict__ Axf, unsigned short* __restrict__ W2t,
        float* __restrict__ logitsC) {
    cg::grid_group grid = cg::this_grid();
    const int bid = blockIdx.x;
    const int t = threadIdx.x;
    const int nb = gridDim.x;                 // PREP_GRID
    const int gt = bid * 256 + t;
    const int gn = nb * 256;

    __shared__ union ShU {
        float tile[32][33];                   // W2 transpose (4224 B)
        struct { int sc[256]; int sm[256]; int pbc[128]; int pbm[128]; } s;
    } sh;

    // ---- P0: zero deg/cnt/flags (replaces the hipMemsetAsync dispatch) ----
    for (int i = gt; i < NN; i += gn) { deg[i] = 0.0f; cnt[i] = 0; }
    if (gt < 8) flags[gt] = 0;
    grid.sync();

    // ---- P1: W2 transpose (blocks 0..127)  ||  edge atomics (blocks 128+) ----
    if (bid < 128) {
        for (int vb = bid; vb < 1024; vb += 128) {
            if (t < 20) logitsC[vb * 20 + t] = 0.0f;   // 1024*20 == MPAD2
            const int n0 = (vb & 31) * 32;
            const int k0 = (vb >> 5) * 32;
            const int tx = t & 31, ty = t >> 5;        // 32 x 8
            __syncthreads();                           // tile reuse across vb iters
#pragma unroll
            for (int j = 0; j < 4; ++j) {
                const int k = k0 + ty + j * 8;
                const int n = n0 + tx;
                sh.tile[ty + j * 8][tx] = (k < 1000 && n < 1000) ? W2[k * 1000 + n] : 0.0f;
            }
            __syncthreads();
#pragma unroll
            for (int j = 0; j < 4; ++j) {
                const int n = n0 + ty + j * 8;
                const int k = k0 + tx;
                W2t[(size_t)n * KP + k] = f2bf(sh.tile[tx][ty + j * 8]);
            }
        }
    } else {
        for (int e = (bid - 128) * 256 + t; e < NE; e += (PREP_GRID - 128) * 256) {
            if (e < 5000) {   // probe mask bit-format
                const unsigned v = ((const unsigned*)mask)[e];
                if (v > 1u) atomicOr(&flags[0], 1);                      // not int32 {0,1}
                if (v != 0u && v != 0x3F800000u) atomicOr(&flags[1], 1); // not f32 {0,1.0f}
            }
            const int c = ei[NE + e];
            atomicAdd(&deg[c], ew[e]);
            atomicAdd(&cnt[c], 1);
        }
    }
    grid.sync();

    // ---- P2: per-block partial sums, dinv, mask decode ----
    for (int vb = bid; vb < NBLK; vb += nb) {
        const int i = vb * 256 + t;
        const int f0 = flags[0], f1 = flags[1];
        int c = 0, mv = 0;
        if (i < NN) {
            c = cnt[i];
            dinv[i] = 1.0f / sqrtf(2.0f + deg[i]);   // self-loop weight 2 folded
            if (f0 == 0)      mv = ((const int*)mask)[i] != 0;
            else if (f1 == 0) mv = ((const unsigned*)mask)[i] != 0u;
            else              mv = ((const unsigned char*)mask)[i] != 0;
            mtmp[i] = mv;
        }
        sh.s.sc[t] = c; sh.s.sm[t] = mv;
        __syncthreads();
        for (int off = 128; off; off >>= 1) {
            if (t < off) { sh.s.sc[t] += sh.s.sc[t + off]; sh.s.sm[t] += sh.s.sm[t + off]; }
            __syncthreads();
        }
        if (t == 0) { bcnt[vb] = sh.s.sc[0]; bmsk[vb] = sh.s.sm[0]; }
        __syncthreads();
    }
    grid.sync();

    // ---- P3: apply — scans -> offs/perm/bc/nm; zero cursor/out ----
    for (int vb = bid; vb < NBLK; vb += nb) {
        if (t < 128) {
            sh.s.pbc[t] = (t < NBLK) ? bcnt[t] : 0;
            sh.s.pbm[t] = (t < NBLK) ? bmsk[t] : 0;
        }
        __syncthreads();
        for (int off = 1; off < 128; off <<= 1) {   // inclusive scan of partials
            int uc = 0, um = 0;
            if (t < 128 && t >= off) { uc = sh.s.pbc[t - off]; um = sh.s.pbm[t - off]; }
            __syncthreads();
            if (t < 128) { sh.s.pbc[t] += uc; sh.s.pbm[t] += um; }
            __syncthreads();
        }
        if (vb == 0 && t == 0) nm[0] = sh.s.pbm[NBLK - 1];
        const int bco = (vb == 0) ? 0 : sh.s.pbc[vb - 1];   // exclusive block offsets
        const int bmo = (vb == 0) ? 0 : sh.s.pbm[vb - 1];
        const int i = vb * 256 + t;
        const int c  = (i < NN) ? cnt[i]  : 0;
        const int mv = (i < NN) ? mtmp[i] : 0;
        sh.s.sc[t] = c; sh.s.sm[t] = mv;
        __syncthreads();
        for (int off = 1; off < 256; off <<= 1) {
            const int uc = (t >= off) ? sh.s.sc[t - off] : 0;
            const int um = (t >= off) ? sh.s.sm[t - off] : 0;
            __syncthreads();
            sh.s.sc[t] += uc; sh.s.sm[t] += um;
            __syncthreads();
        }
        if (i < NN) {
            cursor[i] = 0;
            out[i] = 0.0f;
            offs[i] = bco + sh.s.sc[t] - c;          // exclusive edge-count prefix
            if (mv) {
                const int pos = bmo + sh.s.sm[t] - 1;
                perm[pos] = i;
                bc[pos] = batch[i];
            }
        }
        __syncthreads();
    }
    grid.sync();

    // ---- P4: scatter edges into per-dest CSR slots ----
    for (int e = gt; e < NE; e += gn) {
        const int r = ei[e], c = ei[NE + e];
        const int pos = atomicAdd(&cursor[c], 1);
        const int idx = offs[c] + pos;
        ssrc[idx] = r;
        snorm[idx] = dinv[r] * ew[e] * dinv[c];
    }
    grid.sync();

    // ---- P5: Axf = full first-layer aggregation incl. self-loop ----
    for (int i = gt; i < NN; i += gn) {
        float a0 = 0, a1 = 0, a2 = 0, a3 = 0, a4 = 0;
        const int s0 = offs[i], n = cnt[i];
        for (int e = s0; e < s0 + n; ++e) {
            const int r = ssrc[e];
            const float w = snorm[e];
            const float* xr = x + r * 5;
            a0 += w * xr[0]; a1 += w * xr[1]; a2 += w * xr[2]; a3 += w * xr[3]; a4 += w * xr[4];
        }
        const float wl = 2.0f * dinv[i] * dinv[i];
        const float* xi = x + i * 5;
        a0 += wl * xi[0]; a1 += wl * xi[1]; a2 += wl * xi[2]; a3 += wl * xi[3]; a4 += wl * xi[4];
        float* o = Axf + i * 5;
        o[0] = a0; o[1] = a1; o[2] = a2; o[3] = a3; o[4] = a4;
    }
}

// G[j] = sum_e w_e * relu(Axf[src]@W1 + b1) — h1 never materialized. Barrier-free
// wave-pair structure (R11) + W1 AMORTIZATION (R12): each wave-pair owns 4
// consecutive dests, so the per-wave W1/b1 register fragment is loaded once per
// 4 dests. Dest metadata prefetched in two batched rounds.
// Edge values broadcast via __shfl; no LDS, no __syncthreads.
__global__ __launch_bounds__(256) void aggW1_kernel(const float* __restrict__ Axf,
        const float* __restrict__ W1, const float* __restrict__ b1,
        const int* __restrict__ ssrc, const float* __restrict__ snorm,
        const int* __restrict__ offs, const int* __restrict__ cnt,
        const float* __restrict__ dinv, const int* __restrict__ perm,
        const int* __restrict__ nm, unsigned short* __restrict__ G) {
    const int tid = threadIdx.x;
    const int wv = tid >> 6;
    const int lane = tid & 63;
    const int half = wv & 1;
    const int jbase = blockIdx.x * 8 + (wv >> 1) * 4;   // wave-pair -> 4 dests
    const int nmv = nm[0];
    const int npad = (nmv + 127) & ~127;
    if (jbase >= npad) return;        // wave-uniform (no barriers in this kernel)

    const int c0 = half * 512 + lane * 8;
    float w1r[5][8], bbr[8];
#pragma unroll
    for (int q = 0; q < 2; ++q) {
        const int c = c0 + q * 4;
        const bool v = (c <= 996);    // 1000 % 4 == 0: quads are all-valid or all-pad
#pragma unroll
        for (int f = 0; f < 5; ++f) {
            const float4 w4 = v ? *(const float4*)(W1 + f * 1000 + c)
                                : make_float4(0.f, 0.f, 0.f, 0.f);
            w1r[f][q*4+0] = w4.x; w1r[f][q*4+1] = w4.y;
            w1r[f][q*4+2] = w4.z; w1r[f][q*4+3] = w4.w;
        }
        const float4 b4 = v ? *(const float4*)(b1 + c) : make_float4(0.f, 0.f, 0.f, 0.f);
        bbr[q*4+0] = b4.x; bbr[q*4+1] = b4.y; bbr[q*4+2] = b4.z; bbr[q*4+3] = b4.w;
    }

    // prefetch the 4 dests' metadata (two batched rounds -> latency pipelined)
    int iv[4], s0a[4], na[4]; float dva[4];
#pragma unroll
    for (int d = 0; d < 4; ++d) {
        const int j = jbase + d;                 // j < npad (npad is a mult of 8)
        iv[d] = (j < nmv) ? perm[j] : -1;
    }
#pragma unroll
    for (int d = 0; d < 4; ++d) {
        if (iv[d] >= 0) { s0a[d] = offs[iv[d]]; na[d] = cnt[iv[d]]; dva[d] = dinv[iv[d]]; }
        else            { s0a[d] = 0; na[d] = -1; dva[d] = 0.f; }
    }

#pragma unroll
    for (int d = 0; d < 4; ++d) {
        const int j = jbase + d;
        float acc[8];
#pragma unroll
        for (int k = 0; k < 8; ++k) acc[k] = 0.f;
        const int i = iv[d];
        if (i >= 0) {                            // wave-uniform
            const int s0 = s0a[d], n = na[d];
            const int total = n + 1;             // + self-loop pseudo-edge
            for (int base = 0; base < total; base += 64) {
                const int m = (total - base < 64) ? (total - base) : 64;
                float a0=0.f, a1=0.f, a2=0.f, a3=0.f, a4=0.f, we=0.f;
                if (lane < m) {
                    const int idx = base + lane;
                    int r;
                    if (idx < n) { r = ssrc[s0 + idx]; we = snorm[s0 + idx]; }
                    else         { r = i; we = 2.0f * dva[d] * dva[d]; }
                    const float* axr = Axf + r * 5;
                    a0 = axr[0]; a1 = axr[1]; a2 = axr[2]; a3 = axr[3]; a4 = axr[4];
                }
#pragma unroll 2
                for (int e = 0; e < m; ++e) {
                    const float s0v = __shfl(a0, e);
                    const float s1v = __shfl(a1, e);
                    const float s2v = __shfl(a2, e);
                    const float s3v = __shfl(a3, e);
                    const float s4v = __shfl(a4, e);
                    const float swv = __shfl(we, e);
#pragma unroll
                    for (int k = 0; k < 8; ++k) {
                        const float z = bbr[k] + s0v * w1r[0][k] + s1v * w1r[1][k]
                                      + s2v * w1r[2][k] + s3v * w1r[3][k] + s4v * w1r[4][k];
                        acc[k] += swv * fmaxf(z, 0.f);
                    }
                }
            }
        }
        bf16x8 pk;
#pragma unroll
        for (int k = 0; k < 8; ++k) pk[k] = (short)f2bf(acc[k]);
        *(bf16x8*)(G + (size_t)j * KP + c0) = pk;
    }
}

// logitsC[row] += sum_cols relu(G @ W2 + b2) * Wf over compact rows < nm.
// 128x128 tile / BK=32 / width-16 global_load_lds / XOR-swizzled LDS.
// tm=(bid>>6)*8+(bid&7), tn=(bid>>3)&7: id%8==tm%8 -> A-strip's 8 readers share
// an XCD (FETCH 163->33 MB measured R6). Blocks with tm >= active strips exit.
__global__ __launch_bounds__(256) void gemm_kernel(const unsigned short* __restrict__ A,
                                                   const unsigned short* __restrict__ B,
                                                   const float* __restrict__ b2,
                                                   const float* __restrict__ Wf,
                                                   const int* __restrict__ nm,
                                                   float* __restrict__ logitsC) {
    __shared__ unsigned short As[4096];  // 128 rows x 32 k (bf16) = 8 KB
    __shared__ unsigned short Bs[4096];
    const int tid = threadIdx.x;
    __shared__ int s_nm;
    if (tid == 0) s_nm = nm[0];
    __syncthreads();
    const int nmv = s_nm;
    const int mstrips = (nmv + 127) >> 7;
    const int bid = blockIdx.x;
    const int tm = (bid >> 6) * 8 + (bid & 7);   // 0..159, tm%8 == bid%8
    const int tn = (bid >> 3) & 7;
    if (tm >= mstrips) return;
    const int lane = tid & 63;
    const int wv = tid >> 6;
    const int wr = wv >> 1, wc = wv & 1;

    const int chunk = ((tid & 3) ^ ((tid >> 3) & 3)) * 16;
    const int rsub = tid >> 2;   // row 0..63 (+64 in round 1)
    const char* Ag = (const char*)(A + (size_t)(tm * 128 + rsub) * KP) + chunk;
    const char* Bg = (const char*)(B + (size_t)(tn * 128 + rsub) * KP) + chunk;
    char* AsW = (char*)As + wv * 1024;
    char* BsW = (char*)Bs + wv * 1024;

    f32x4 acc[4][4];
#pragma unroll
    for (int i = 0; i < 4; ++i)
#pragma unroll
        for (int j = 0; j < 4; ++j) acc[i][j] = (f32x4){0.f, 0.f, 0.f, 0.f};

    const int m = lane & 15;
    const int quad = lane >> 4;
    const int sw = quad ^ ((m >> 1) & 3);       // swizzled k-chunk slot
    const int aoff = (wr * 64 + m) * 64 + sw * 16;
    const int boff = (wc * 64 + m) * 64 + sw * 16;

    for (int kk = 0; kk < KP; kk += 32) {
        __syncthreads();
        const int kb = kk * 2;
        gld_lds16(Ag + kb,             AsW);
        gld_lds16(Ag + kb + 64 * 2048, AsW + 4096);
        gld_lds16(Bg + kb,             BsW);
        gld_lds16(Bg + kb + 64 * 2048, BsW + 4096);
        __syncthreads();
        bf16x8 af[4], bfv[4];
#pragma unroll
        for (int mt = 0; mt < 4; ++mt)
            af[mt] = *(const bf16x8*)((const char*)As + aoff + mt * 1024);
#pragma unroll
        for (int nt = 0; nt < 4; ++nt)
            bfv[nt] = *(const bf16x8*)((const char*)Bs + boff + nt * 1024);
#pragma unroll
        for (int mt = 0; mt < 4; ++mt)
#pragma unroll
            for (int nt = 0; nt < 4; ++nt)
                acc[mt][nt] = __builtin_amdgcn_mfma_f32_16x16x32_bf16(af[mt], bfv[nt], acc[mt][nt], 0, 0, 0);
    }

    // epilogue: C/D layout col = lane&15, row = quad*4 + reg
    const int col0 = tn * 128 + wc * 64 + m;
    const int row00 = tm * 128 + wr * 64 + quad * 4;
#pragma unroll
    for (int mt = 0; mt < 4; ++mt) {
        float ps0 = 0.f, ps1 = 0.f, ps2 = 0.f, ps3 = 0.f;
#pragma unroll
        for (int nt = 0; nt < 4; ++nt) {
            const int c = col0 + nt * 16;
            const float bbv = (c < 1000) ? b2[c] : 0.0f;
            const float wfv = (c < 1000) ? Wf[c] : 0.0f;
            ps0 += fmaxf(acc[mt][nt][0] + bbv, 0.f) * wfv;
            ps1 += fmaxf(acc[mt][nt][1] + bbv, 0.f) * wfv;
            ps2 += fmaxf(acc[mt][nt][2] + bbv, 0.f) * wfv;
            ps3 += fmaxf(acc[mt][nt][3] + bbv, 0.f) * wfv;
        }
#pragma unroll
        for (int msk = 1; msk < 16; msk <<= 1) {
            ps0 += __shfl_xor(ps0, msk);
            ps1 += __shfl_xor(ps1, msk);
            ps2 += __shfl_xor(ps2, msk);
            ps3 += __shfl_xor(ps3, msk);
        }
        if (m == 0) {
            const int row = row00 + mt * 16;
            if (row + 0 < nmv) atomicAdd(&logitsC[row + 0], ps0);
            if (row + 1 < nmv) atomicAdd(&logitsC[row + 1], ps1);
            if (row + 2 < nmv) atomicAdd(&logitsC[row + 2], ps2);
            if (row + 3 < nmv) atomicAdd(&logitsC[row + 3], ps3);
        }
    }
}

// segment softmax over compact (all-masked) logits; bc sorted -> binary search.
// out pre-zeroed by prep_kernel P3; only masked slots written via perm.
__global__ __launch_bounds__(256) void softmax_kernel(const float* __restrict__ logitsC,
        const int* __restrict__ perm, const int* __restrict__ bc,
        const int* __restrict__ nm, float* __restrict__ out) {
    const int g = blockIdx.x;
    const int t = threadIdx.x;
    __shared__ int s_lo, s_hi;
    __shared__ float red[4];
    __shared__ float sval;
    if (t == 0) {
        const int nmv = nm[0];
        int lo = 0, hi = nmv;
        while (lo < hi) { const int mid = (lo + hi) >> 1; if (bc[mid] < g) lo = mid + 1; else hi = mid; }
        s_lo = lo;
        int lo2 = lo, hi2 = nmv;
        while (lo2 < hi2) { const int mid = (lo2 + hi2) >> 1; if (bc[mid] < g + 1) lo2 = mid + 1; else hi2 = mid; }
        s_hi = lo2;
    }
    __syncthreads();
    const int lo = s_lo, hi = s_hi;
    float mx = -1e30f;
    for (int i = lo + t; i < hi; i += 256) mx = fmaxf(mx, logitsC[i]);
    for (int off = 32; off; off >>= 1) mx = fmaxf(mx, __shfl_down(mx, off));
    if ((t & 63) == 0) red[t >> 6] = mx;
    __syncthreads();
    if (t == 0) sval = fmaxf(fmaxf(red[0], red[1]), fmaxf(red[2], red[3]));
    __syncthreads();
    mx = sval;
    __syncthreads();
    float sm = 0.f;
    for (int i = lo + t; i < hi; i += 256) sm += expf(logitsC[i] - mx);
    for (int off = 32; off; off >>= 1) sm += __shfl_down(sm, off);
    if ((t & 63) == 0) red[t >> 6] = sm;
    __syncthreads();
    if (t == 0) sval = red[0] + red[1] + red[2] + red[3];
    __syncthreads();
    const float inv = 1.0f / fmaxf(sval, 1e-16f);
    for (int i = lo + t; i < hi; i += 256)
        out[perm[i]] = expf(logitsC[i] - mx) * inv;
}

extern "C" void kernel_launch(void* const* d_in, const int* in_sizes, int n_in,
                              void* d_out, int out_size, void* d_ws, size_t ws_size,
                              hipStream_t stream) {
    (void)in_sizes; (void)n_in; (void)out_size; (void)ws_size;
    const float* x   = (const float*)d_in[0];
    const float* ew  = (const float*)d_in[1];
    const float* W1  = (const float*)d_in[2];
    const float* b1  = (const float*)d_in[3];
    const float* W2  = (const float*)d_in[4];
    const float* b2  = (const float*)d_in[5];
    const float* Wf  = (const float*)d_in[6];
    const int*   ei  = (const int*)d_in[8];
    const void*  mask  = d_in[9];
    const int*   batch = (const int*)d_in[10];
    float* out = (float*)d_out;

    char* p = (char*)d_ws;
    auto carve = [&](size_t bytes) { char* q = p; p += (bytes + 255) & ~(size_t)255; return q; };
    float* deg     = (float*)carve(NN * 4);
    int*   cnt     = (int*)carve(NN * 4);
    int*   flags   = (int*)carve(256);
    int*   cursor  = (int*)carve(NN * 4);
    float* logitsC = (float*)carve(MPAD2 * 4);
    int*   offs   = (int*)carve(NN * 4);
    float* dinv   = (float*)carve(NN * 4);
    int*   mtmp   = (int*)carve(NN * 4);
    int*   perm   = (int*)carve(NN * 4);
    int*   bc     = (int*)carve(NN * 4);
    int*   bcnt   = (int*)carve(NBLK * 4);
    int*   bmsk   = (int*)carve(NBLK * 4);
    int*   nmp    = (int*)carve(256);
    int*   ssrc   = (int*)carve(NE * 4);
    float* snorm  = (float*)carve(NE * 4);
    float* Axf    = (float*)carve(NN * 5 * 4);
    unsigned short* W2t = (unsigned short*)carve((size_t)KP * KP * 2);
    unsigned short* G   = (unsigned short*)carve((size_t)MPAD2 * KP * 2);

    void* pargs[] = {
        (void*)&ei, (void*)&ew, (void*)&x, (void*)&W2, (void*)&batch, (void*)&mask,
        (void*)&deg, (void*)&cnt, (void*)&flags, (void*)&mtmp, (void*)&dinv,
        (void*)&bcnt, (void*)&bmsk, (void*)&offs, (void*)&perm, (void*)&bc,
        (void*)&nmp, (void*)&cursor, (void*)&out, (void*)&ssrc, (void*)&snorm,
        (void*)&Axf, (void*)&W2t, (void*)&logitsC
    };
    hipLaunchCooperativeKernel((void*)prep_kernel, dim3(PREP_GRID), dim3(256),
                               pargs, 0, stream);
    hipLaunchKernelGGL(aggW1_kernel, dim3(MPAD2/8), dim3(256), 0, stream,
                       Axf, W1, b1, ssrc, snorm, offs, cnt, dinv, perm, nmp, G);
    hipLaunchKernelGGL(gemm_kernel,  dim3(MT2*8),   dim3(256), 0, stream,
                       G, W2t, b2, Wf, nmp, logitsC);
    hipLaunchKernelGGL(softmax_kernel, dim3(NG),    dim3(256), 0, stream,
                       logitsC, perm, bc, nmp, out);
}

// Round 2
// 350.580 us; speedup vs baseline: 1.5995x; 1.5995x over previous
//
#include <hip/hip_runtime.h>

#define NN 20000
#define NE 160000
#define NG 16
#define KP 1024            // padded feature dim
#define MT2 160            // max M strips of 128 in compact space
#define MPAD2 (MT2*128)    // 20480
#define NBLK 79            // ceil(20000/256)

typedef __attribute__((ext_vector_type(8))) short bf16x8;
typedef __attribute__((ext_vector_type(4))) float f32x4;

#define GAS __attribute__((address_space(1)))
#define LAS __attribute__((address_space(3)))

__device__ __forceinline__ unsigned short f2bf(float f) {
    unsigned int u = __float_as_uint(f);
    u += 0x7FFFu + ((u >> 16) & 1u);   // round-to-nearest-even
    return (unsigned short)(u >> 16);
}

__device__ __forceinline__ void gld_lds16(const char* g, char* l) {
    __builtin_amdgcn_global_load_lds((GAS void*)g, (LAS void*)l, 16, 0, 0);
}

// deg/cnt/flags zeroed by hipMemsetAsync before this.
// Also probes the mask bit-format (int32 {0,1} / float32 {0,1.0f} / byte).
__global__ void deg_cnt_kernel(const int* __restrict__ ei, const float* __restrict__ ew,
                               float* deg, int* cnt, const void* __restrict__ mask,
                               int* flags) {
    const int e = blockIdx.x * blockDim.x + threadIdx.x;
    if (e < 5000) {
        const unsigned v = ((const unsigned*)mask)[e];
        if (v > 1u) atomicOr(&flags[0], 1);                      // not int32 {0,1}
        if (v != 0u && v != 0x3F800000u) atomicOr(&flags[1], 1); // not float32 {0,1.0f}
    }
    if (e >= NE) return;
    const int c = ei[NE + e];
    atomicAdd(&deg[c], ew[e]);
    atomicAdd(&cnt[c], 1);
}

// R14 "mid" kernel — three INDEPENDENT jobs in one dispatch (no internal deps,
// no grid sync; R13 post-mortem: grid.sync() ~70us each on MI355X, never again):
//   block 0       : single-block global scan -> offs/perm/bc/nm, zero cursor/out
//                   (replaces the partial+apply two-dispatch scan; depends only
//                   on cnt+mask+batch, all final after deg_cnt)
//   blocks 1..79  : dinv = 1/sqrt(2+deg), zero Axf (node-parallel)
//   blocks 80..1103: W2t[n][k] = bf16(W2[k][n]) zero-padded, + zero logitsC
__global__ __launch_bounds__(256) void mid_kernel(
        const float* __restrict__ deg, const int* __restrict__ cnt,
        const int* __restrict__ flags, const void* __restrict__ mask,
        const int* __restrict__ batch, const float* __restrict__ W2,
        float* __restrict__ dinv, float* __restrict__ Axf,
        int* __restrict__ offs, int* __restrict__ perm, int* __restrict__ bcv,
        int* __restrict__ nm, int* __restrict__ cursor, float* __restrict__ out,
        unsigned short* __restrict__ W2t, float* __restrict__ logitsC) {
    const int bid = blockIdx.x;
    const int t = threadIdx.x;
    __shared__ float tile[32][33];
    __shared__ int wtc[4], wtm[4];

    if (bid == 0) {
        // ---- single-block scan: 256 threads x 79 contiguous elements ----
        const int f0 = flags[0], f1 = flags[1];
        const bool wordmask = (f0 == 0 || f1 == 0);  // int32 and f32 both: word != 0
        const int lane = t & 63, wvi = t >> 6;
        const int i0 = t * 79;                       // 256*79 = 20224 >= NN
        int tc = 0, tm = 0;
        for (int j = 0; j < 79; ++j) {
            const int i = i0 + j;
            if (i < NN) {
                tc += cnt[i];
                tm += wordmask ? (((const unsigned*)mask)[i] != 0u)
                               : (((const unsigned char*)mask)[i] != 0);
            }
        }
        const int myc = tc, mym = tm;
        for (int o = 1; o < 64; o <<= 1) {           // wave inclusive scan
            const int uc = __shfl_up(tc, o);
            const int um = __shfl_up(tm, o);
            if (lane >= o) { tc += uc; tm += um; }
        }
        if (lane == 63) { wtc[wvi] = tc; wtm[wvi] = tm; }
        __syncthreads();
        int bc0 = 0, bm0 = 0;
        for (int w = 0; w < wvi; ++w) { bc0 += wtc[w]; bm0 += wtm[w]; }
        int runc = bc0 + tc - myc;                   // exclusive prefix, this range
        int runm = bm0 + tm - mym;
        if (t == 0) nm[0] = wtm[0] + wtm[1] + wtm[2] + wtm[3];
        for (int j = 0; j < 79; ++j) {
            const int i = i0 + j;
            if (i < NN) {
                const int c = cnt[i];
                const int mv = wordmask ? (((const unsigned*)mask)[i] != 0u)
                                        : (((const unsigned char*)mask)[i] != 0);
                offs[i] = runc; runc += c;
                cursor[i] = 0;
                out[i] = 0.0f;
                if (mv) { perm[runm] = i; bcv[runm] = batch[i]; ++runm; }
            }
        }
    } else if (bid < 80) {
        // ---- dinv + Axf zero ----
        const int i = (bid - 1) * 256 + t;
        if (i < NN) {
            dinv[i] = 1.0f / sqrtf(2.0f + deg[i]);   // self-loop weight 2 folded
            float* a = Axf + i * 5;
            a[0] = 0.f; a[1] = 0.f; a[2] = 0.f; a[3] = 0.f; a[4] = 0.f;
        }
    } else {
        // ---- W2 transpose tile (one 32x32 tile per block) ----
        const int vb = bid - 80;                     // 0..1023
        if (t < 20) logitsC[vb * 20 + t] = 0.0f;     // 1024*20 == MPAD2
        const int n0 = (vb & 31) * 32;
        const int k0 = (vb >> 5) * 32;
        const int tx = t & 31, ty = t >> 5;          // 32 x 8
#pragma unroll
        for (int j = 0; j < 4; ++j) {
            const int k = k0 + ty + j * 8;
            const int n = n0 + tx;
            tile[ty + j * 8][tx] = (k < 1000 && n < 1000) ? W2[k * 1000 + n] : 0.0f;
        }
        __syncthreads();
#pragma unroll
        for (int j = 0; j < 4; ++j) {
            const int n = n0 + ty + j * 8;
            const int k = k0 + tx;
            W2t[(size_t)n * KP + k] = f2bf(tile[tx][ty + j * 8]);
        }
    }
}

// scatter + Axf accumulation fused (R14): CSR build and first-layer aggregation
// are both edge-parallel with no mutual dependency; Axf via commutative fp32
// atomics (zeroed in mid_kernel), self-loop term added node-parallel here too.
__global__ void scatter_axf_kernel(const int* __restrict__ ei, const float* __restrict__ ew,
                                   const float* __restrict__ x, const float* __restrict__ dinv,
                                   const int* __restrict__ offs, int* cursor,
                                   int* __restrict__ ssrc, float* __restrict__ snorm,
                                   float* __restrict__ Axf) {
    const int e = blockIdx.x * blockDim.x + threadIdx.x;
    if (e < NE) {
        const int r = ei[e], c = ei[NE + e];
        const int pos = atomicAdd(&cursor[c], 1);
        const int idx = offs[c] + pos;
        const float w = dinv[r] * ew[e] * dinv[c];
        ssrc[idx] = r;
        snorm[idx] = w;
        const float* xr = x + r * 5;
        float* ac = Axf + c * 5;
        atomicAdd(ac + 0, w * xr[0]);
        atomicAdd(ac + 1, w * xr[1]);
        atomicAdd(ac + 2, w * xr[2]);
        atomicAdd(ac + 3, w * xr[3]);
        atomicAdd(ac + 4, w * xr[4]);
    }
    if (e < NN) {
        const float wl = 2.0f * dinv[e] * dinv[e];
        const float* xi = x + e * 5;
        float* ai = Axf + e * 5;
        atomicAdd(ai + 0, wl * xi[0]);
        atomicAdd(ai + 1, wl * xi[1]);
        atomicAdd(ai + 2, wl * xi[2]);
        atomicAdd(ai + 3, wl * xi[3]);
        atomicAdd(ai + 4, wl * xi[4]);
    }
}

// G[j] = sum_e w_e * relu(Axf[src]@W1 + b1) — h1 never materialized. Barrier-free
// wave-pair structure (R11) + W1 AMORTIZATION (R12): each wave-pair owns 4
// consecutive dests, so the per-wave W1/b1 register fragment is loaded once per
// 4 dests. Dest metadata prefetched in two batched rounds.
// Edge values broadcast via __shfl; no LDS, no __syncthreads.
__global__ __launch_bounds__(256) void aggW1_kernel(const float* __restrict__ Axf,
        const float* __restrict__ W1, const float* __restrict__ b1,
        const int* __restrict__ ssrc, const float* __restrict__ snorm,
        const int* __restrict__ offs, const int* __restrict__ cnt,
        const float* __restrict__ dinv, const int* __restrict__ perm,
        const int* __restrict__ nm, unsigned short* __restrict__ G) {
    const int tid = threadIdx.x;
    const int wv = tid >> 6;
    const int lane = tid & 63;
    const int half = wv & 1;
    const int jbase = blockIdx.x * 8 + (wv >> 1) * 4;   // wave-pair -> 4 dests
    const int nmv = nm[0];
    const int npad = (nmv + 127) & ~127;
    if (jbase >= npad) return;        // wave-uniform (no barriers in this kernel)

    const int c0 = half * 512 + lane * 8;
    float w1r[5][8], bbr[8];
#pragma unroll
    for (int q = 0; q < 2; ++q) {
        const int c = c0 + q * 4;
        const bool v = (c <= 996);    // 1000 % 4 == 0: quads are all-valid or all-pad
#pragma unroll
        for (int f = 0; f < 5; ++f) {
            const float4 w4 = v ? *(const float4*)(W1 + f * 1000 + c)
                                : make_float4(0.f, 0.f, 0.f, 0.f);
            w1r[f][q*4+0] = w4.x; w1r[f][q*4+1] = w4.y;
            w1r[f][q*4+2] = w4.z; w1r[f][q*4+3] = w4.w;
        }
        const float4 b4 = v ? *(const float4*)(b1 + c) : make_float4(0.f, 0.f, 0.f, 0.f);
        bbr[q*4+0] = b4.x; bbr[q*4+1] = b4.y; bbr[q*4+2] = b4.z; bbr[q*4+3] = b4.w;
    }

    // prefetch the 4 dests' metadata (two batched rounds -> latency pipelined)
    int iv[4], s0a[4], na[4]; float dva[4];
#pragma unroll
    for (int d = 0; d < 4; ++d) {
        const int j = jbase + d;                 // j < npad (npad is a mult of 8)
        iv[d] = (j < nmv) ? perm[j] : -1;
    }
#pragma unroll
    for (int d = 0; d < 4; ++d) {
        if (iv[d] >= 0) { s0a[d] = offs[iv[d]]; na[d] = cnt[iv[d]]; dva[d] = dinv[iv[d]]; }
        else            { s0a[d] = 0; na[d] = -1; dva[d] = 0.f; }
    }

#pragma unroll
    for (int d = 0; d < 4; ++d) {
        const int j = jbase + d;
        float acc[8];
#pragma unroll
        for (int k = 0; k < 8; ++k) acc[k] = 0.f;
        const int i = iv[d];
        if (i >= 0) {                            // wave-uniform
            const int s0 = s0a[d], n = na[d];
            const int total = n + 1;             // + self-loop pseudo-edge
            for (int base = 0; base < total; base += 64) {
                const int m = (total - base < 64) ? (total - base) : 64;
                float a0=0.f, a1=0.f, a2=0.f, a3=0.f, a4=0.f, we=0.f;
                if (lane < m) {
                    const int idx = base + lane;
                    int r;
                    if (idx < n) { r = ssrc[s0 + idx]; we = snorm[s0 + idx]; }
                    else         { r = i; we = 2.0f * dva[d] * dva[d]; }
                    const float* axr = Axf + r * 5;
                    a0 = axr[0]; a1 = axr[1]; a2 = axr[2]; a3 = axr[3]; a4 = axr[4];
                }
#pragma unroll 2
                for (int e = 0; e < m; ++e) {
                    const float s0v = __shfl(a0, e);
                    const float s1v = __shfl(a1, e);
                    const float s2v = __shfl(a2, e);
                    const float s3v = __shfl(a3, e);
                    const float s4v = __shfl(a4, e);
                    const float swv = __shfl(we, e);
#pragma unroll
                    for (int k = 0; k < 8; ++k) {
                        const float z = bbr[k] + s0v * w1r[0][k] + s1v * w1r[1][k]
                                      + s2v * w1r[2][k] + s3v * w1r[3][k] + s4v * w1r[4][k];
                        acc[k] += swv * fmaxf(z, 0.f);
                    }
                }
            }
        }
        bf16x8 pk;
#pragma unroll
        for (int k = 0; k < 8; ++k) pk[k] = (short)f2bf(acc[k]);
        *(bf16x8*)(G + (size_t)j * KP + c0) = pk;
    }
}

// logitsC[row] += sum_cols relu(G @ W2 + b2) * Wf over compact rows < nm.
// 128x128 tile / BK=32 / width-16 global_load_lds / XOR-swizzled LDS.
// tm=(bid>>6)*8+(bid&7), tn=(bid>>3)&7: id%8==tm%8 -> A-strip's 8 readers share
// an XCD (FETCH 163->33 MB measured R6). Blocks with tm >= active strips exit.
__global__ __launch_bounds__(256) void gemm_kernel(const unsigned short* __restrict__ A,
                                                   const unsigned short* __restrict__ B,
                                                   const float* __restrict__ b2,
                                                   const float* __restrict__ Wf,
                                                   const int* __restrict__ nm,
                                                   float* __restrict__ logitsC) {
    __shared__ unsigned short As[4096];  // 128 rows x 32 k (bf16) = 8 KB
    __shared__ unsigned short Bs[4096];
    const int tid = threadIdx.x;
    __shared__ int s_nm;
    if (tid == 0) s_nm = nm[0];
    __syncthreads();
    const int nmv = s_nm;
    const int mstrips = (nmv + 127) >> 7;
    const int bid = blockIdx.x;
    const int tm = (bid >> 6) * 8 + (bid & 7);   // 0..159, tm%8 == bid%8
    const int tn = (bid >> 3) & 7;
    if (tm >= mstrips) return;
    const int lane = tid & 63;
    const int wv = tid >> 6;
    const int wr = wv >> 1, wc = wv & 1;

    const int chunk = ((tid & 3) ^ ((tid >> 3) & 3)) * 16;
    const int rsub = tid >> 2;   // row 0..63 (+64 in round 1)
    const char* Ag = (const char*)(A + (size_t)(tm * 128 + rsub) * KP) + chunk;
    const char* Bg = (const char*)(B + (size_t)(tn * 128 + rsub) * KP) + chunk;
    char* AsW = (char*)As + wv * 1024;
    char* BsW = (char*)Bs + wv * 1024;

    f32x4 acc[4][4];
#pragma unroll
    for (int i = 0; i < 4; ++i)
#pragma unroll
        for (int j = 0; j < 4; ++j) acc[i][j] = (f32x4){0.f, 0.f, 0.f, 0.f};

    const int m = lane & 15;
    const int quad = lane >> 4;
    const int sw = quad ^ ((m >> 1) & 3);       // swizzled k-chunk slot
    const int aoff = (wr * 64 + m) * 64 + sw * 16;
    const int boff = (wc * 64 + m) * 64 + sw * 16;

    for (int kk = 0; kk < KP; kk += 32) {
        __syncthreads();
        const int kb = kk * 2;
        gld_lds16(Ag + kb,             AsW);
        gld_lds16(Ag + kb + 64 * 2048, AsW + 4096);
        gld_lds16(Bg + kb,             BsW);
        gld_lds16(Bg + kb + 64 * 2048, BsW + 4096);
        __syncthreads();
        bf16x8 af[4], bfv[4];
#pragma unroll
        for (int mt = 0; mt < 4; ++mt)
            af[mt] = *(const bf16x8*)((const char*)As + aoff + mt * 1024);
#pragma unroll
        for (int nt = 0; nt < 4; ++nt)
            bfv[nt] = *(const bf16x8*)((const char*)Bs + boff + nt * 1024);
#pragma unroll
        for (int mt = 0; mt < 4; ++mt)
#pragma unroll
            for (int nt = 0; nt < 4; ++nt)
                acc[mt][nt] = __builtin_amdgcn_mfma_f32_16x16x32_bf16(af[mt], bfv[nt], acc[mt][nt], 0, 0, 0);
    }

    // epilogue: C/D layout col = lane&15, row = quad*4 + reg
    const int col0 = tn * 128 + wc * 64 + m;
    const int row00 = tm * 128 + wr * 64 + quad * 4;
#pragma unroll
    for (int mt = 0; mt < 4; ++mt) {
        float ps0 = 0.f, ps1 = 0.f, ps2 = 0.f, ps3 = 0.f;
#pragma unroll
        for (int nt = 0; nt < 4; ++nt) {
            const int c = col0 + nt * 16;
            const float bbv = (c < 1000) ? b2[c] : 0.0f;
            const float wfv = (c < 1000) ? Wf[c] : 0.0f;
            ps0 += fmaxf(acc[mt][nt][0] + bbv, 0.f) * wfv;
            ps1 += fmaxf(acc[mt][nt][1] + bbv, 0.f) * wfv;
            ps2 += fmaxf(acc[mt][nt][2] + bbv, 0.f) * wfv;
            ps3 += fmaxf(acc[mt][nt][3] + bbv, 0.f) * wfv;
        }
#pragma unroll
        for (int msk = 1; msk < 16; msk <<= 1) {
            ps0 += __shfl_xor(ps0, msk);
            ps1 += __shfl_xor(ps1, msk);
            ps2 += __shfl_xor(ps2, msk);
            ps3 += __shfl_xor(ps3, msk);
        }
        if (m == 0) {
            const int row = row00 + mt * 16;
            if (row + 0 < nmv) atomicAdd(&logitsC[row + 0], ps0);
            if (row + 1 < nmv) atomicAdd(&logitsC[row + 1], ps1);
            if (row + 2 < nmv) atomicAdd(&logitsC[row + 2], ps2);
            if (row + 3 < nmv) atomicAdd(&logitsC[row + 3], ps3);
        }
    }
}

// segment softmax over compact (all-masked) logits; bc sorted -> binary search.
// out pre-zeroed by mid_kernel scan block; only masked slots written via perm.
__global__ __launch_bounds__(256) void softmax_kernel(const float* __restrict__ logitsC,
        const int* __restrict__ perm, const int* __restrict__ bc,
        const int* __restrict__ nm, float* __restrict__ out) {
    const int g = blockIdx.x;
    const int t = threadIdx.x;
    __shared__ int s_lo, s_hi;
    __shared__ float red[4];
    __shared__ float sval;
    if (t == 0) {
        const int nmv = nm[0];
        int lo = 0, hi = nmv;
        while (lo < hi) { const int mid = (lo + hi) >> 1; if (bc[mid] < g) lo = mid + 1; else hi = mid; }
        s_lo = lo;
        int lo2 = lo, hi2 = nmv;
        while (lo2 < hi2) { const int mid = (lo2 + hi2) >> 1; if (bc[mid] < g + 1) lo2 = mid + 1; else hi2 = mid; }
        s_hi = lo2;
    }
    __syncthreads();
    const int lo = s_lo, hi = s_hi;
    float mx = -1e30f;
    for (int i = lo + t; i < hi; i += 256) mx = fmaxf(mx, logitsC[i]);
    for (int off = 32; off; off >>= 1) mx = fmaxf(mx, __shfl_down(mx, off));
    if ((t & 63) == 0) red[t >> 6] = mx;
    __syncthreads();
    if (t == 0) sval = fmaxf(fmaxf(red[0], red[1]), fmaxf(red[2], red[3]));
    __syncthreads();
    mx = sval;
    __syncthreads();
    float sm = 0.f;
    for (int i = lo + t; i < hi; i += 256) sm += expf(logitsC[i] - mx);
    for (int off = 32; off; off >>= 1) sm += __shfl_down(sm, off);
    if ((t & 63) == 0) red[t >> 6] = sm;
    __syncthreads();
    if (t == 0) sval = red[0] + red[1] + red[2] + red[3];
    __syncthreads();
    const float inv = 1.0f / fmaxf(sval, 1e-16f);
    for (int i = lo + t; i < hi; i += 256)
        out[perm[i]] = expf(logitsC[i] - mx) * inv;
}

extern "C" void kernel_launch(void* const* d_in, const int* in_sizes, int n_in,
                              void* d_out, int out_size, void* d_ws, size_t ws_size,
                              hipStream_t stream) {
    (void)in_sizes; (void)n_in; (void)out_size; (void)ws_size;
    const float* x   = (const float*)d_in[0];
    const float* ew  = (const float*)d_in[1];
    const float* W1  = (const float*)d_in[2];
    const float* b1  = (const float*)d_in[3];
    const float* W2  = (const float*)d_in[4];
    const float* b2  = (const float*)d_in[5];
    const float* Wf  = (const float*)d_in[6];
    const int*   ei  = (const int*)d_in[8];
    const void*  mask  = d_in[9];
    const int*   batch = (const int*)d_in[10];
    float* out = (float*)d_out;

    char* p = (char*)d_ws;
    auto carve = [&](size_t bytes) { char* q = p; p += (bytes + 255) & ~(size_t)255; return q; };
    // zero-region (single hipMemsetAsync): deg, cnt, flags only
    char* zbase = p;
    float* deg     = (float*)carve(NN * 4);
    int*   cnt     = (int*)carve(NN * 4);
    int*   flags   = (int*)carve(256);
    size_t zspan = (size_t)(p - zbase);
    int*   cursor  = (int*)carve(NN * 4);
    float* logitsC = (float*)carve(MPAD2 * 4);
    int*   offs   = (int*)carve(NN * 4);
    float* dinv   = (float*)carve(NN * 4);
    int*   perm   = (int*)carve(NN * 4);
    int*   bc     = (int*)carve(NN * 4);
    int*   nmp    = (int*)carve(256);
    int*   ssrc   = (int*)carve(NE * 4);
    float* snorm  = (float*)carve(NE * 4);
    float* Axf    = (float*)carve(NN * 5 * 4);
    unsigned short* W2t = (unsigned short*)carve((size_t)KP * KP * 2);
    unsigned short* G   = (unsigned short*)carve((size_t)MPAD2 * KP * 2);

    hipMemsetAsync(zbase, 0, zspan, stream);
    hipLaunchKernelGGL(deg_cnt_kernel,   dim3(625),     dim3(256), 0, stream, ei, ew, deg, cnt, mask, flags);
    hipLaunchKernelGGL(mid_kernel,       dim3(1104),    dim3(256), 0, stream, deg, cnt, flags, mask, batch, W2, dinv, Axf, offs, perm, bc, nmp, cursor, out, W2t, logitsC);
    hipLaunchKernelGGL(scatter_axf_kernel, dim3(625),   dim3(256), 0, stream, ei, ew, x, dinv, offs, cursor, ssrc, snorm, Axf);
    hipLaunchKernelGGL(aggW1_kernel,     dim3(MPAD2/8), dim3(256), 0, stream, Axf, W1, b1, ssrc, snorm, offs, cnt, dinv, perm, nmp, G);
    hipLaunchKernelGGL(gemm_kernel,      dim3(MT2*8),   dim3(256), 0, stream, G, W2t, b2, Wf, nmp, logitsC);
    hipLaunchKernelGGL(softmax_kernel,   dim3(NG),      dim3(256), 0, stream, logitsC, perm, bc, nmp, out);
}

// Round 3
// 232.111 us; speedup vs baseline: 2.4159x; 1.5104x over previous
//
#include <hip/hip_runtime.h>

#define NN 20000
#define NE 160000
#define NG 16
#define KP 1024            // padded feature dim
#define MT2 160            // max M strips of 128 in compact space
#define MPAD2 (MT2*128)    // 20480
#define NBLK 79            // ceil(20000/256)

typedef __attribute__((ext_vector_type(8))) short bf16x8;
typedef __attribute__((ext_vector_type(4))) float f32x4;

#define GAS __attribute__((address_space(1)))
#define LAS __attribute__((address_space(3)))

__device__ __forceinline__ unsigned short f2bf(float f) {
    unsigned int u = __float_as_uint(f);
    u += 0x7FFFu + ((u >> 16) & 1u);   // round-to-nearest-even
    return (unsigned short)(u >> 16);
}

__device__ __forceinline__ void gld_lds16(const char* g, char* l) {
    __builtin_amdgcn_global_load_lds((GAS void*)g, (LAS void*)l, 16, 0, 0);
}

// R15: deg/cnt atomics (blocks 0..624) || W2 transpose + logitsC zero (blocks
// 625..1648) in ONE dispatch — zero mutual dependency, hides the ~10us
// transpose under the edge atomics. deg/cnt/flags zeroed by hipMemsetAsync.
__global__ __launch_bounds__(256) void degcnt_w2t_kernel(
        const int* __restrict__ ei, const float* __restrict__ ew,
        const void* __restrict__ mask, float* deg, int* cnt, int* flags,
        const float* __restrict__ W2, unsigned short* __restrict__ W2t,
        float* __restrict__ logitsC) {
    const int bid = blockIdx.x;
    const int t = threadIdx.x;
    __shared__ float tile[32][33];
    if (bid < 625) {
        const int e = bid * 256 + t;
        if (e < 5000) {   // probe mask bit-format
            const unsigned v = ((const unsigned*)mask)[e];
            if (v > 1u) atomicOr(&flags[0], 1);                      // not int32 {0,1}
            if (v != 0u && v != 0x3F800000u) atomicOr(&flags[1], 1); // not f32 {0,1.0f}
        }
        if (e >= NE) return;
        const int c = ei[NE + e];
        atomicAdd(&deg[c], ew[e]);
        atomicAdd(&cnt[c], 1);
    } else {
        const int vb = bid - 625;                    // 0..1023
        if (t < 20) logitsC[vb * 20 + t] = 0.0f;     // 1024*20 == MPAD2
        const int n0 = (vb & 31) * 32;
        const int k0 = (vb >> 5) * 32;
        const int tx = t & 31, ty = t >> 5;          // 32 x 8
#pragma unroll
        for (int j = 0; j < 4; ++j) {
            const int k = k0 + ty + j * 8;
            const int n = n0 + tx;
            tile[ty + j * 8][tx] = (k < 1000 && n < 1000) ? W2[k * 1000 + n] : 0.0f;
        }
        __syncthreads();
#pragma unroll
        for (int j = 0; j < 4; ++j) {
            const int n = n0 + ty + j * 8;
            const int k = k0 + tx;
            W2t[(size_t)n * KP + k] = f2bf(tile[tx][ty + j * 8]);
        }
    }
}

// R15 apply: single dispatch (partial pass DELETED). Each block recomputes its
// exclusive offset by strided-COALESCED re-summation of cnt/mask over
// [0, b*256) — 79 blocks in parallel, <=78 coalesced loads/thread, ~3MB L2
// total. (R2 lesson: never a serial single-block scan; this is bandwidth-
// parallel.) Then the R0 in-block scan -> offs/perm/bc/nm; zero cursor/out.
__global__ __launch_bounds__(256) void apply_kernel(const int* __restrict__ cnt,
        const void* __restrict__ mask, const int* __restrict__ flags,
        const int* __restrict__ batch, int* __restrict__ offs,
        int* __restrict__ perm, int* __restrict__ bc, int* __restrict__ nm,
        int* __restrict__ cursor, float* __restrict__ out) {
    const int b = blockIdx.x, t = threadIdx.x;
    const int f0 = flags[0], f1 = flags[1];
    const bool wordmask = (f0 == 0 || f1 == 0);      // int32/f32: word != 0
    const int lim = b * 256;
    int pc = 0, pm = 0;
    for (int i = t; i < lim; i += 256) {             // coalesced strided prefix
        pc += cnt[i];
        pm += wordmask ? (((const unsigned*)mask)[i] != 0u)
                       : (((const unsigned char*)mask)[i] != 0);
    }
    __shared__ int sc[256], sm[256];
    sc[t] = pc; sm[t] = pm;
    __syncthreads();
    for (int off = 128; off; off >>= 1) {
        if (t < off) { sc[t] += sc[t + off]; sm[t] += sm[t + off]; }
        __syncthreads();
    }
    const int bco = sc[0], bmo = sm[0];              // exclusive block offsets
    __syncthreads();                                 // all reads done before reuse
    const int i = b * 256 + t;
    int c = 0, mv = 0;
    if (i < NN) {
        c = cnt[i];
        mv = wordmask ? (((const unsigned*)mask)[i] != 0u)
                      : (((const unsigned char*)mask)[i] != 0);
    }
    sc[t] = c; sm[t] = mv;
    __syncthreads();
    for (int off = 1; off < 256; off <<= 1) {        // in-block inclusive scan
        const int uc = (t >= off) ? sc[t - off] : 0;
        const int um = (t >= off) ? sm[t - off] : 0;
        __syncthreads();
        sc[t] += uc; sm[t] += um;
        __syncthreads();
    }
    if (i < NN) {
        cursor[i] = 0;
        out[i] = 0.0f;
        offs[i] = bco + sc[t] - c;                   // exclusive edge-count prefix
        if (mv) {
            const int pos = bmo + sm[t] - 1;         // compact slot
            perm[pos] = i;
            bc[pos] = batch[i];
        }
    }
    if (b == NBLK - 1 && t == 255) nm[0] = bmo + sm[255];
}

__global__ void scatter_kernel(const int* __restrict__ ei, const float* __restrict__ ew,
                               const float* __restrict__ dinv, const int* __restrict__ offs,
                               int* cursor, int* __restrict__ ssrc, float* __restrict__ snorm) {
    const int e = blockIdx.x * blockDim.x + threadIdx.x;
    if (e >= NE) return;
    const int r = ei[e], c = ei[NE + e];
    const int pos = atomicAdd(&cursor[c], 1);
    const int idx = offs[c] + pos;
    ssrc[idx] = r;
    snorm[idx] = dinv[r] * ew[e] * dinv[c];
}

// dinv must exist before scatter: computed here (node-parallel, 79 blocks) in
// the same dispatch slot as in R0 (folded into apply would race with scatter's
// read ordering across dispatches — keep it in its own tiny kernel fused with
// nothing; it's ~2us). Actually: dinv depends only on deg -> compute in apply's
// dispatch? apply doesn't read deg. Keep it here fused into scatter's
// PREDECESSOR: we fold dinv into apply_kernel's sibling below.
__global__ __launch_bounds__(256) void dinv_kernel(const float* __restrict__ deg,
                                                   float* __restrict__ dinv) {
    const int i = blockIdx.x * blockDim.x + threadIdx.x;
    if (i < NN) dinv[i] = 1.0f / sqrtf(2.0f + deg[i]);   // self-loop weight 2 folded
}

// Axf = full first-layer aggregation incl. self-loop (R0 gather version — R2
// proved the atomic-scatter variant costs +25us).
__global__ __launch_bounds__(256) void axf_kernel(const float* __restrict__ x,
        const int* __restrict__ ssrc, const float* __restrict__ snorm,
        const int* __restrict__ offs, const int* __restrict__ cnt,
        const float* __restrict__ dinv, float* __restrict__ Axf) {
    const int i = blockIdx.x * blockDim.x + threadIdx.x;
    if (i >= NN) return;
    float a0=0,a1=0,a2=0,a3=0,a4=0;
    const int s0 = offs[i], n = cnt[i];
    for (int e = s0; e < s0 + n; ++e) {
        const int r = ssrc[e];
        const float w = snorm[e];
        const float* xr = x + r * 5;
        a0 += w*xr[0]; a1 += w*xr[1]; a2 += w*xr[2]; a3 += w*xr[3]; a4 += w*xr[4];
    }
    const float wl = 2.0f * dinv[i] * dinv[i];
    const float* xi = x + i * 5;
    a0 += wl*xi[0]; a1 += wl*xi[1]; a2 += wl*xi[2]; a3 += wl*xi[3]; a4 += wl*xi[4];
    float* o = Axf + i * 5;
    o[0]=a0; o[1]=a1; o[2]=a2; o[3]=a3; o[4]=a4;
}

// G[j] = sum_e w_e * relu(Axf[src]@W1 + b1) — h1 never materialized. Barrier-free
// wave-pair structure (R11) + W1 AMORTIZATION (R12): each wave-pair owns 4
// consecutive dests, so the per-wave W1/b1 register fragment is loaded once per
// 4 dests. Dest metadata prefetched in two batched rounds.
// Edge values broadcast via __shfl; no LDS, no __syncthreads.
__global__ __launch_bounds__(256) void aggW1_kernel(const float* __restrict__ Axf,
        const float* __restrict__ W1, const float* __restrict__ b1,
        const int* __restrict__ ssrc, const float* __restrict__ snorm,
        const int* __restrict__ offs, const int* __restrict__ cnt,
        const float* __restrict__ dinv, const int* __restrict__ perm,
        const int* __restrict__ nm, unsigned short* __restrict__ G) {
    const int tid = threadIdx.x;
    const int wv = tid >> 6;
    const int lane = tid & 63;
    const int half = wv & 1;
    const int jbase = blockIdx.x * 8 + (wv >> 1) * 4;   // wave-pair -> 4 dests
    const int nmv = nm[0];
    const int npad = (nmv + 127) & ~127;
    if (jbase >= npad) return;        // wave-uniform (no barriers in this kernel)

    const int c0 = half * 512 + lane * 8;
    float w1r[5][8], bbr[8];
#pragma unroll
    for (int q = 0; q < 2; ++q) {
        const int c = c0 + q * 4;
        const bool v = (c <= 996);    // 1000 % 4 == 0: quads are all-valid or all-pad
#pragma unroll
        for (int f = 0; f < 5; ++f) {
            const float4 w4 = v ? *(const float4*)(W1 + f * 1000 + c)
                                : make_float4(0.f, 0.f, 0.f, 0.f);
            w1r[f][q*4+0] = w4.x; w1r[f][q*4+1] = w4.y;
            w1r[f][q*4+2] = w4.z; w1r[f][q*4+3] = w4.w;
        }
        const float4 b4 = v ? *(const float4*)(b1 + c) : make_float4(0.f, 0.f, 0.f, 0.f);
        bbr[q*4+0] = b4.x; bbr[q*4+1] = b4.y; bbr[q*4+2] = b4.z; bbr[q*4+3] = b4.w;
    }

    // prefetch the 4 dests' metadata (two batched rounds -> latency pipelined)
    int iv[4], s0a[4], na[4]; float dva[4];
#pragma unroll
    for (int d = 0; d < 4; ++d) {
        const int j = jbase + d;                 // j < npad (npad is a mult of 8)
        iv[d] = (j < nmv) ? perm[j] : -1;
    }
#pragma unroll
    for (int d = 0; d < 4; ++d) {
        if (iv[d] >= 0) { s0a[d] = offs[iv[d]]; na[d] = cnt[iv[d]]; dva[d] = dinv[iv[d]]; }
        else            { s0a[d] = 0; na[d] = -1; dva[d] = 0.f; }
    }

#pragma unroll
    for (int d = 0; d < 4; ++d) {
        const int j = jbase + d;
        float acc[8];
#pragma unroll
        for (int k = 0; k < 8; ++k) acc[k] = 0.f;
        const int i = iv[d];
        if (i >= 0) {                            // wave-uniform
            const int s0 = s0a[d], n = na[d];
            const int total = n + 1;             // + self-loop pseudo-edge
            for (int base = 0; base < total; base += 64) {
                const int m = (total - base < 64) ? (total - base) : 64;
                float a0=0.f, a1=0.f, a2=0.f, a3=0.f, a4=0.f, we=0.f;
                if (lane < m) {
                    const int idx = base + lane;
                    int r;
                    if (idx < n) { r = ssrc[s0 + idx]; we = snorm[s0 + idx]; }
                    else         { r = i; we = 2.0f * dva[d] * dva[d]; }
                    const float* axr = Axf + r * 5;
                    a0 = axr[0]; a1 = axr[1]; a2 = axr[2]; a3 = axr[3]; a4 = axr[4];
                }
#pragma unroll 2
                for (int e = 0; e < m; ++e) {
                    const float s0v = __shfl(a0, e);
                    const float s1v = __shfl(a1, e);
                    const float s2v = __shfl(a2, e);
                    const float s3v = __shfl(a3, e);
                    const float s4v = __shfl(a4, e);
                    const float swv = __shfl(we, e);
#pragma unroll
                    for (int k = 0; k < 8; ++k) {
                        const float z = bbr[k] + s0v * w1r[0][k] + s1v * w1r[1][k]
                                      + s2v * w1r[2][k] + s3v * w1r[3][k] + s4v * w1r[4][k];
                        acc[k] += swv * fmaxf(z, 0.f);
                    }
                }
            }
        }
        bf16x8 pk;
#pragma unroll
        for (int k = 0; k < 8; ++k) pk[k] = (short)f2bf(acc[k]);
        *(bf16x8*)(G + (size_t)j * KP + c0) = pk;
    }
}

// logitsC[row] += sum_cols relu(G @ W2 + b2) * Wf over compact rows < nm.
// 128x128 tile / width-16 global_load_lds / XOR-swizzled LDS.
// R15: TWO 32-k sub-tiles per barrier period (BK=64 via second 8KB buffer at
// +8192B, identical swizzle; readers at aoff+8192) -> barrier-drain count
// 32 -> 16. LDS 32KB total, 3 blocks/CU unchanged (VGPR-limited).
// tm=(bid>>6)*8+(bid&7), tn=(bid>>3)&7: id%8==tm%8 -> A-strip's 8 readers share
// an XCD (FETCH 163->33 MB measured R6). Blocks with tm >= active strips exit.
__global__ __launch_bounds__(256) void gemm_kernel(const unsigned short* __restrict__ A,
                                                   const unsigned short* __restrict__ B,
                                                   const float* __restrict__ b2,
                                                   const float* __restrict__ Wf,
                                                   const int* __restrict__ nm,
                                                   float* __restrict__ logitsC) {
    __shared__ unsigned short As[8192];  // 2 x (128 rows x 32 k) bf16 = 16 KB
    __shared__ unsigned short Bs[8192];
    const int tid = threadIdx.x;
    __shared__ int s_nm;
    if (tid == 0) s_nm = nm[0];
    __syncthreads();
    const int nmv = s_nm;
    const int mstrips = (nmv + 127) >> 7;
    const int bid = blockIdx.x;
    const int tm = (bid >> 6) * 8 + (bid & 7);   // 0..159, tm%8 == bid%8
    const int tn = (bid >> 3) & 7;
    if (tm >= mstrips) return;
    const int lane = tid & 63;
    const int wv = tid >> 6;
    const int wr = wv >> 1, wc = wv & 1;

    const int chunk = ((tid & 3) ^ ((tid >> 3) & 3)) * 16;
    const int rsub = tid >> 2;   // row 0..63 (+64 in round 1)
    const char* Ag = (const char*)(A + (size_t)(tm * 128 + rsub) * KP) + chunk;
    const char* Bg = (const char*)(B + (size_t)(tn * 128 + rsub) * KP) + chunk;
    char* AsW = (char*)As + wv * 1024;
    char* BsW = (char*)Bs + wv * 1024;

    f32x4 acc[4][4];
#pragma unroll
    for (int i = 0; i < 4; ++i)
#pragma unroll
        for (int j = 0; j < 4; ++j) acc[i][j] = (f32x4){0.f, 0.f, 0.f, 0.f};

    const int m = lane & 15;
    const int quad = lane >> 4;
    const int sw = quad ^ ((m >> 1) & 3);       // swizzled k-chunk slot
    const int aoff = (wr * 64 + m) * 64 + sw * 16;
    const int boff = (wc * 64 + m) * 64 + sw * 16;

    for (int kk = 0; kk < KP; kk += 64) {
        __syncthreads();
        const int kb = kk * 2;                  // byte offset of k-tile 0
        gld_lds16(Ag + kb,                  AsW);
        gld_lds16(Ag + kb + 64 * 2048,      AsW + 4096);
        gld_lds16(Ag + kb + 64,             AsW + 8192);          // k-tile 1 (+32 k)
        gld_lds16(Ag + kb + 64 + 64 * 2048, AsW + 8192 + 4096);
        gld_lds16(Bg + kb,                  BsW);
        gld_lds16(Bg + kb + 64 * 2048,      BsW + 4096);
        gld_lds16(Bg + kb + 64,             BsW + 8192);
        gld_lds16(Bg + kb + 64 + 64 * 2048, BsW + 8192 + 4096);
        __syncthreads();
#pragma unroll
        for (int h = 0; h < 2; ++h) {
            const int hb = h * 8192;
            bf16x8 af[4], bfv[4];
#pragma unroll
            for (int mt = 0; mt < 4; ++mt)
                af[mt] = *(const bf16x8*)((const char*)As + hb + aoff + mt * 1024);
#pragma unroll
            for (int nt = 0; nt < 4; ++nt)
                bfv[nt] = *(const bf16x8*)((const char*)Bs + hb + boff + nt * 1024);
#pragma unroll
            for (int mt = 0; mt < 4; ++mt)
#pragma unroll
                for (int nt = 0; nt < 4; ++nt)
                    acc[mt][nt] = __builtin_amdgcn_mfma_f32_16x16x32_bf16(af[mt], bfv[nt], acc[mt][nt], 0, 0, 0);
        }
    }

    // epilogue: C/D layout col = lane&15, row = quad*4 + reg
    const int col0 = tn * 128 + wc * 64 + m;
    const int row00 = tm * 128 + wr * 64 + quad * 4;
#pragma unroll
    for (int mt = 0; mt < 4; ++mt) {
        float ps0 = 0.f, ps1 = 0.f, ps2 = 0.f, ps3 = 0.f;
#pragma unroll
        for (int nt = 0; nt < 4; ++nt) {
            const int c = col0 + nt * 16;
            const float bbv = (c < 1000) ? b2[c] : 0.0f;
            const float wfv = (c < 1000) ? Wf[c] : 0.0f;
            ps0 += fmaxf(acc[mt][nt][0] + bbv, 0.f) * wfv;
            ps1 += fmaxf(acc[mt][nt][1] + bbv, 0.f) * wfv;
            ps2 += fmaxf(acc[mt][nt][2] + bbv, 0.f) * wfv;
            ps3 += fmaxf(acc[mt][nt][3] + bbv, 0.f) * wfv;
        }
#pragma unroll
        for (int msk = 1; msk < 16; msk <<= 1) {
            ps0 += __shfl_xor(ps0, msk);
            ps1 += __shfl_xor(ps1, msk);
            ps2 += __shfl_xor(ps2, msk);
            ps3 += __shfl_xor(ps3, msk);
        }
        if (m == 0) {
            const int row = row00 + mt * 16;
            if (row + 0 < nmv) atomicAdd(&logitsC[row + 0], ps0);
            if (row + 1 < nmv) atomicAdd(&logitsC[row + 1], ps1);
            if (row + 2 < nmv) atomicAdd(&logitsC[row + 2], ps2);
            if (row + 3 < nmv) atomicAdd(&logitsC[row + 3], ps3);
        }
    }
}

// segment softmax over compact (all-masked) logits; bc sorted -> binary search.
// out pre-zeroed by apply_kernel; only masked slots written via perm.
__global__ __launch_bounds__(256) void softmax_kernel(const float* __restrict__ logitsC,
        const int* __restrict__ perm, const int* __restrict__ bc,
        const int* __restrict__ nm, float* __restrict__ out) {
    const int g = blockIdx.x;
    const int t = threadIdx.x;
    __shared__ int s_lo, s_hi;
    __shared__ float red[4];
    __shared__ float sval;
    if (t == 0) {
        const int nmv = nm[0];
        int lo = 0, hi = nmv;
        while (lo < hi) { const int mid = (lo + hi) >> 1; if (bc[mid] < g) lo = mid + 1; else hi = mid; }
        s_lo = lo;
        int lo2 = lo, hi2 = nmv;
        while (lo2 < hi2) { const int mid = (lo2 + hi2) >> 1; if (bc[mid] < g + 1) lo2 = mid + 1; else hi2 = mid; }
        s_hi = lo2;
    }
    __syncthreads();
    const int lo = s_lo, hi = s_hi;
    float mx = -1e30f;
    for (int i = lo + t; i < hi; i += 256) mx = fmaxf(mx, logitsC[i]);
    for (int off = 32; off; off >>= 1) mx = fmaxf(mx, __shfl_down(mx, off));
    if ((t & 63) == 0) red[t >> 6] = mx;
    __syncthreads();
    if (t == 0) sval = fmaxf(fmaxf(red[0], red[1]), fmaxf(red[2], red[3]));
    __syncthreads();
    mx = sval;
    __syncthreads();
    float sm = 0.f;
    for (int i = lo + t; i < hi; i += 256) sm += expf(logitsC[i] - mx);
    for (int off = 32; off; off >>= 1) sm += __shfl_down(sm, off);
    if ((t & 63) == 0) red[t >> 6] = sm;
    __syncthreads();
    if (t == 0) sval = red[0] + red[1] + red[2] + red[3];
    __syncthreads();
    const float inv = 1.0f / fmaxf(sval, 1e-16f);
    for (int i = lo + t; i < hi; i += 256)
        out[perm[i]] = expf(logitsC[i] - mx) * inv;
}

extern "C" void kernel_launch(void* const* d_in, const int* in_sizes, int n_in,
                              void* d_out, int out_size, void* d_ws, size_t ws_size,
                              hipStream_t stream) {
    (void)in_sizes; (void)n_in; (void)out_size; (void)ws_size;
    const float* x   = (const float*)d_in[0];
    const float* ew  = (const float*)d_in[1];
    const float* W1  = (const float*)d_in[2];
    const float* b1  = (const float*)d_in[3];
    const float* W2  = (const float*)d_in[4];
    const float* b2  = (const float*)d_in[5];
    const float* Wf  = (const float*)d_in[6];
    const int*   ei  = (const int*)d_in[8];
    const void*  mask  = d_in[9];
    const int*   batch = (const int*)d_in[10];
    float* out = (float*)d_out;

    char* p = (char*)d_ws;
    auto carve = [&](size_t bytes) { char* q = p; p += (bytes + 255) & ~(size_t)255; return q; };
    // zero-region (single hipMemsetAsync): deg, cnt, flags only
    char* zbase = p;
    float* deg     = (float*)carve(NN * 4);
    int*   cnt     = (int*)carve(NN * 4);
    int*   flags   = (int*)carve(256);
    size_t zspan = (size_t)(p - zbase);
    int*   cursor  = (int*)carve(NN * 4);
    float* logitsC = (float*)carve(MPAD2 * 4);
    int*   offs   = (int*)carve(NN * 4);
    float* dinv   = (float*)carve(NN * 4);
    int*   perm   = (int*)carve(NN * 4);
    int*   bc     = (int*)carve(NN * 4);
    int*   nmp    = (int*)carve(256);
    int*   ssrc   = (int*)carve(NE * 4);
    float* snorm  = (float*)carve(NE * 4);
    float* Axf    = (float*)carve(NN * 5 * 4);
    unsigned short* W2t = (unsigned short*)carve((size_t)KP * KP * 2);
    unsigned short* G   = (unsigned short*)carve((size_t)MPAD2 * KP * 2);

    hipMemsetAsync(zbase, 0, zspan, stream);
    hipLaunchKernelGGL(degcnt_w2t_kernel, dim3(1649),   dim3(256), 0, stream, ei, ew, mask, deg, cnt, flags, W2, W2t, logitsC);
    hipLaunchKernelGGL(dinv_kernel,       dim3(NBLK),   dim3(256), 0, stream, deg, dinv);
    hipLaunchKernelGGL(apply_kernel,      dim3(NBLK),   dim3(256), 0, stream, cnt, mask, flags, batch, offs, perm, bc, nmp, cursor, out);
    hipLaunchKernelGGL(scatter_kernel,    dim3(625),    dim3(256), 0, stream, ei, ew, dinv, offs, cursor, ssrc, snorm);
    hipLaunchKernelGGL(axf_kernel,        dim3(NBLK),   dim3(256), 0, stream, x, ssrc, snorm, offs, cnt, dinv, Axf);
    hipLaunchKernelGGL(aggW1_kernel,      dim3(MPAD2/8),dim3(256), 0, stream, Axf, W1, b1, ssrc, snorm, offs, cnt, dinv, perm, nmp, G);
    hipLaunchKernelGGL(gemm_kernel,       dim3(MT2*8),  dim3(256), 0, stream, G, W2t, b2, Wf, nmp, logitsC);
    hipLaunchKernelGGL(softmax_kernel,    dim3(NG),     dim3(256), 0, stream, logitsC, perm, bc, nmp, out);
}

// Round 4
// 213.507 us; speedup vs baseline: 2.6264x; 1.0871x over previous
//
#include <hip/hip_runtime.h>

#define NN 20000
#define NE 160000
#define NG 16
#define KP 1024            // padded feature dim
#define MT2 160            // max M strips of 128 in compact space
#define MPAD2 (MT2*128)    // 20480
#define NBLK 79            // ceil(20000/256)

typedef __attribute__((ext_vector_type(8))) short bf16x8;
typedef __attribute__((ext_vector_type(4))) float f32x4;

#define GAS __attribute__((address_space(1)))
#define LAS __attribute__((address_space(3)))

__device__ __forceinline__ unsigned short f2bf(float f) {
    unsigned int u = __float_as_uint(f);
    u += 0x7FFFu + ((u >> 16) & 1u);   // round-to-nearest-even
    return (unsigned short)(u >> 16);
}

__device__ __forceinline__ void gld_lds16(const char* g, char* l) {
    __builtin_amdgcn_global_load_lds((GAS void*)g, (LAS void*)l, 16, 0, 0);
}

// deg/cnt/flags zeroed by hipMemsetAsync before this.
// Also probes the mask bit-format (int32 {0,1} / float32 {0,1.0f} / byte).
__global__ void deg_cnt_kernel(const int* __restrict__ ei, const float* __restrict__ ew,
                               float* deg, int* cnt, const void* __restrict__ mask,
                               int* flags) {
    const int e = blockIdx.x * blockDim.x + threadIdx.x;
    if (e < 5000) {
        const unsigned v = ((const unsigned*)mask)[e];
        if (v > 1u) atomicOr(&flags[0], 1);                      // not int32 {0,1}
        if (v != 0u && v != 0x3F800000u) atomicOr(&flags[1], 1); // not float32 {0,1.0f}
    }
    if (e >= NE) return;
    const int c = ei[NE + e];
    atomicAdd(&deg[c], ew[e]);
    atomicAdd(&cnt[c], 1);
}

// blocks 0..NBLK-1: per-block sums (edge counts + mask), dinv, mask decode.
// blocks NBLK..NBLK+1023: W2t[n][k] = bf16(W2[k][n]) zero-padded, + zero logitsC.
__global__ __launch_bounds__(256) void partial_w2t_kernel(const int* __restrict__ cnt,
        const float* __restrict__ deg, const void* __restrict__ mask,
        const int* __restrict__ flags, int* __restrict__ mtmp,
        float* __restrict__ dinv, int* __restrict__ bcnt, int* __restrict__ bmsk,
        const float* __restrict__ W2, unsigned short* __restrict__ W2t,
        float* __restrict__ logitsC) {
    const int bid = blockIdx.x;
    const int t = threadIdx.x;
    if (bid < NBLK) {
        const int i = bid * 256 + t;
        const int f0 = flags[0], f1 = flags[1];
        int c = 0, mv = 0;
        if (i < NN) {
            c = cnt[i];
            dinv[i] = 1.0f / sqrtf(2.0f + deg[i]);   // self-loop weight 2 folded; > 0
            if (f0 == 0)      mv = ((const int*)mask)[i] != 0;
            else if (f1 == 0) mv = ((const unsigned*)mask)[i] != 0u;
            else              mv = ((const unsigned char*)mask)[i] != 0;
            mtmp[i] = mv;
        }
        __shared__ int sc[256], sm[256];
        sc[t] = c; sm[t] = mv;
        __syncthreads();
        for (int off = 128; off; off >>= 1) {
            if (t < off) { sc[t] += sc[t + off]; sm[t] += sm[t + off]; }
            __syncthreads();
        }
        if (t == 0) { bcnt[bid] = sc[0]; bmsk[bid] = sm[0]; }
    } else {
        __shared__ float tile[32][33];
        const int bw = bid - NBLK;
        if (t < 20) logitsC[bw * 20 + t] = 0.0f;   // 1024*20 == 20480 == MPAD2
        const int n0 = (bw & 31) * 32;
        const int k0 = (bw >> 5) * 32;
        const int tx = t & 31, ty = t >> 5;        // 32 x 8
#pragma unroll
        for (int j = 0; j < 4; ++j) {
            const int k = k0 + ty + j * 8;
            const int n = n0 + tx;
            tile[ty + j * 8][tx] = (k < 1000 && n < 1000) ? W2[k * 1000 + n] : 0.0f;
        }
        __syncthreads();
#pragma unroll
        for (int j = 0; j < 4; ++j) {
            const int n = n0 + ty + j * 8;
            const int k = k0 + tx;
            W2t[(size_t)n * KP + k] = f2bf(tile[tx][ty + j * 8]);
        }
    }
}

// apply: re-scan the NBLK partials in-block, then in-block scan + offsets ->
// offs, perm, bc; block 0 writes nm. Also zeroes cursor (pre-scatter) and
// out (pre-softmax; unmasked slots must be 0).
__global__ __launch_bounds__(256) void apply_kernel(const int* __restrict__ cnt,
        const int* __restrict__ mtmp, const int* __restrict__ bcnt,
        const int* __restrict__ bmsk, const int* __restrict__ batch,
        int* __restrict__ offs, int* __restrict__ perm, int* __restrict__ bc,
        int* __restrict__ nm, int* __restrict__ cursor, float* __restrict__ out) {
    const int b = blockIdx.x, t = threadIdx.x;
    __shared__ int pbc[128], pbm[128];
    if (t < 128) {
        pbc[t] = (t < NBLK) ? bcnt[t] : 0;
        pbm[t] = (t < NBLK) ? bmsk[t] : 0;
    }
    __syncthreads();
    for (int off = 1; off < 128; off <<= 1) {       // inclusive scan of partials
        int uc = 0, um = 0;
        if (t < 128 && t >= off) { uc = pbc[t - off]; um = pbm[t - off]; }
        __syncthreads();
        if (t < 128) { pbc[t] += uc; pbm[t] += um; }
        __syncthreads();
    }
    if (b == 0 && t == 0) nm[0] = pbm[NBLK - 1];
    const int bco = (b == 0) ? 0 : pbc[b - 1];      // exclusive block offsets
    const int bmo = (b == 0) ? 0 : pbm[b - 1];
    const int i = b * 256 + t;
    const int c  = (i < NN) ? cnt[i]  : 0;
    const int mv = (i < NN) ? mtmp[i] : 0;
    __shared__ int sc[256], sm[256];
    sc[t] = c; sm[t] = mv;
    __syncthreads();
    for (int off = 1; off < 256; off <<= 1) {
        const int uc = (t >= off) ? sc[t - off] : 0;
        const int um = (t >= off) ? sm[t - off] : 0;
        __syncthreads();
        sc[t] += uc; sm[t] += um;
        __syncthreads();
    }
    if (i < NN) {
        cursor[i] = 0;
        out[i] = 0.0f;
        offs[i] = bco + sc[t] - c;                  // exclusive edge-count prefix
        if (mv) {
            const int pos = bmo + sm[t] - 1;        // compact slot
            perm[pos] = i;
            bc[pos] = batch[i];
        }
    }
}

__global__ void scatter_kernel(const int* __restrict__ ei, const float* __restrict__ ew,
                               const float* __restrict__ dinv, const int* __restrict__ offs,
                               int* cursor, int* __restrict__ ssrc, float* __restrict__ snorm) {
    const int e = blockIdx.x * blockDim.x + threadIdx.x;
    if (e >= NE) return;
    const int r = ei[e], c = ei[NE + e];
    const int pos = atomicAdd(&cursor[c], 1);
    const int idx = offs[c] + pos;
    ssrc[idx] = r;
    snorm[idx] = dinv[r] * ew[e] * dinv[c];
}

// Axf = full first-layer aggregation incl. self-loop
__global__ __launch_bounds__(256) void axf_kernel(const float* __restrict__ x,
        const int* __restrict__ ssrc, const float* __restrict__ snorm,
        const int* __restrict__ offs, const int* __restrict__ cnt,
        const float* __restrict__ dinv, float* __restrict__ Axf) {
    const int i = blockIdx.x * blockDim.x + threadIdx.x;
    if (i >= NN) return;
    float a0=0,a1=0,a2=0,a3=0,a4=0;
    const int s0 = offs[i], n = cnt[i];
    for (int e = s0; e < s0 + n; ++e) {
        const int r = ssrc[e];
        const float w = snorm[e];
        const float* xr = x + r * 5;
        a0 += w*xr[0]; a1 += w*xr[1]; a2 += w*xr[2]; a3 += w*xr[3]; a4 += w*xr[4];
    }
    const float wl = 2.0f * dinv[i] * dinv[i];
    const float* xi = x + i * 5;
    a0 += wl*xi[0]; a1 += wl*xi[1]; a2 += wl*xi[2]; a3 += wl*xi[3]; a4 += wl*xi[4];
    float* o = Axf + i * 5;
    o[0]=a0; o[1]=a1; o[2]=a2; o[3]=a3; o[4]=a4;
}

// G[j] = sum_e w_e * relu(Axf[src]@W1 + b1) — h1 never materialized. Barrier-free
// wave-pair structure (R11) + W1 AMORTIZATION (R12): each wave-pair owns 4
// consecutive dests, so the per-wave W1/b1 register fragment (10 KB/wave of L2
// traffic — the R11 residue, ~500 MB total at 2 dests/block) is loaded once per
// 4 dests (~50 MB total). Dest metadata prefetched in two batched rounds.
// Edge values broadcast via __shfl; no LDS, no __syncthreads.
__global__ __launch_bounds__(256) void aggW1_kernel(const float* __restrict__ Axf,
        const float* __restrict__ W1, const float* __restrict__ b1,
        const int* __restrict__ ssrc, const float* __restrict__ snorm,
        const int* __restrict__ offs, const int* __restrict__ cnt,
        const float* __restrict__ dinv, const int* __restrict__ perm,
        const int* __restrict__ nm, unsigned short* __restrict__ G) {
    const int tid = threadIdx.x;
    const int wv = tid >> 6;
    const int lane = tid & 63;
    const int half = wv & 1;
    const int jbase = blockIdx.x * 8 + (wv >> 1) * 4;   // wave-pair -> 4 dests
    const int nmv = nm[0];
    const int npad = (nmv + 127) & ~127;
    if (jbase >= npad) return;        // wave-uniform (no barriers in this kernel)

    const int c0 = half * 512 + lane * 8;
    float w1r[5][8], bbr[8];
#pragma unroll
    for (int q = 0; q < 2; ++q) {
        const int c = c0 + q * 4;
        const bool v = (c <= 996);    // 1000 % 4 == 0: quads are all-valid or all-pad
#pragma unroll
        for (int f = 0; f < 5; ++f) {
            const float4 w4 = v ? *(const float4*)(W1 + f * 1000 + c)
                                : make_float4(0.f, 0.f, 0.f, 0.f);
            w1r[f][q*4+0] = w4.x; w1r[f][q*4+1] = w4.y;
            w1r[f][q*4+2] = w4.z; w1r[f][q*4+3] = w4.w;
        }
        const float4 b4 = v ? *(const float4*)(b1 + c) : make_float4(0.f, 0.f, 0.f, 0.f);
        bbr[q*4+0] = b4.x; bbr[q*4+1] = b4.y; bbr[q*4+2] = b4.z; bbr[q*4+3] = b4.w;
    }

    // prefetch the 4 dests' metadata (two batched rounds -> latency pipelined)
    int iv[4], s0a[4], na[4]; float dva[4];
#pragma unroll
    for (int d = 0; d < 4; ++d) {
        const int j = jbase + d;                 // j < npad (npad is a mult of 8)
        iv[d] = (j < nmv) ? perm[j] : -1;
    }
#pragma unroll
    for (int d = 0; d < 4; ++d) {
        if (iv[d] >= 0) { s0a[d] = offs[iv[d]]; na[d] = cnt[iv[d]]; dva[d] = dinv[iv[d]]; }
        else            { s0a[d] = 0; na[d] = -1; dva[d] = 0.f; }
    }

#pragma unroll
    for (int d = 0; d < 4; ++d) {
        const int j = jbase + d;
        float acc[8];
#pragma unroll
        for (int k = 0; k < 8; ++k) acc[k] = 0.f;
        const int i = iv[d];
        if (i >= 0) {                            // wave-uniform
            const int s0 = s0a[d], n = na[d];
            const int total = n + 1;             // + self-loop pseudo-edge
            for (int base = 0; base < total; base += 64) {
                const int m = (total - base < 64) ? (total - base) : 64;
                float a0=0.f, a1=0.f, a2=0.f, a3=0.f, a4=0.f, we=0.f;
                if (lane < m) {
                    const int idx = base + lane;
                    int r;
                    if (idx < n) { r = ssrc[s0 + idx]; we = snorm[s0 + idx]; }
                    else         { r = i; we = 2.0f * dva[d] * dva[d]; }
                    const float* axr = Axf + r * 5;
                    a0 = axr[0]; a1 = axr[1]; a2 = axr[2]; a3 = axr[3]; a4 = axr[4];
                }
#pragma unroll 2
                for (int e = 0; e < m; ++e) {
                    const float s0v = __shfl(a0, e);
                    const float s1v = __shfl(a1, e);
                    const float s2v = __shfl(a2, e);
                    const float s3v = __shfl(a3, e);
                    const float s4v = __shfl(a4, e);
                    const float swv = __shfl(we, e);
#pragma unroll
                    for (int k = 0; k < 8; ++k) {
                        const float z = bbr[k] + s0v * w1r[0][k] + s1v * w1r[1][k]
                                      + s2v * w1r[2][k] + s3v * w1r[3][k] + s4v * w1r[4][k];
                        acc[k] += swv * fmaxf(z, 0.f);
                    }
                }
            }
        }
        bf16x8 pk;
#pragma unroll
        for (int k = 0; k < 8; ++k) pk[k] = (short)f2bf(acc[k]);
        *(bf16x8*)(G + (size_t)j * KP + c0) = pk;
    }
}

// logitsC[row] += sum_cols relu(G @ W2 + b2) * Wf over compact rows < nm.
// 128x128 tile / BK=32 / width-16 global_load_lds / XOR-swizzled LDS.
// R16: depth-3 PREFETCH PIPELINE (R3 counters: 45us, MfmaUtil 16%, FETCH
// ~= compulsory, HBM 6% -> per-iter latency-bound; __syncthreads drains
// vmcnt(0) every K-step, exposing ~900cy x 32 iters with only ~2.5 blocks/CU).
// 4-buffer LDS ring, counted vmcnt (8 -> 4 -> 0 only in the 2-iter tail), raw
// s_barrier (NOT __syncthreads — that would re-drain). Ordering per m201
// template: own-wave vmcnt(N) THEN barrier => buffer collectively ready.
// Post-MFMA barrier: frag ds_reads were consumed by MFMA (lgkm drained by
// compiler), so after it all waves' reads are done -> safe to DMA-overwrite.
// tm=(bid>>6)*8+(bid&7), tn=(bid>>3)&7: id%8==tm%8 -> A-strip's 8 readers share
// an XCD (FETCH 163->33 MB measured R6). Blocks with tm >= active strips exit.
__global__ __launch_bounds__(256) void gemm_kernel(const unsigned short* __restrict__ A,
                                                   const unsigned short* __restrict__ B,
                                                   const float* __restrict__ b2,
                                                   const float* __restrict__ Wf,
                                                   const int* __restrict__ nm,
                                                   float* __restrict__ logitsC) {
    __shared__ unsigned short As[4 * 4096];  // 4 bufs x (128 rows x 32 k) bf16 = 32 KB
    __shared__ unsigned short Bs[4 * 4096];
    const int tid = threadIdx.x;
    __shared__ int s_nm;
    if (tid == 0) s_nm = nm[0];
    __syncthreads();
    const int nmv = s_nm;
    const int mstrips = (nmv + 127) >> 7;
    const int bid = blockIdx.x;
    const int tm = (bid >> 6) * 8 + (bid & 7);   // 0..159, tm%8 == bid%8
    const int tn = (bid >> 3) & 7;
    if (tm >= mstrips) return;
    const int lane = tid & 63;
    const int wv = tid >> 6;
    const int wr = wv >> 1, wc = wv & 1;

    const int chunk = ((tid & 3) ^ ((tid >> 3) & 3)) * 16;
    const int rsub = tid >> 2;   // row 0..63 (+64 in round 1)
    const char* Ag = (const char*)(A + (size_t)(tm * 128 + rsub) * KP) + chunk;
    const char* Bg = (const char*)(B + (size_t)(tn * 128 + rsub) * KP) + chunk;
    char* AsW = (char*)As + wv * 1024;           // this wave's staging quarter
    char* BsW = (char*)Bs + wv * 1024;

    f32x4 acc[4][4];
#pragma unroll
    for (int i = 0; i < 4; ++i)
#pragma unroll
        for (int j = 0; j < 4; ++j) acc[i][j] = (f32x4){0.f, 0.f, 0.f, 0.f};

    const int m = lane & 15;
    const int quad = lane >> 4;
    const int sw = quad ^ ((m >> 1) & 3);       // swizzled k-chunk slot
    const int aoff = (wr * 64 + m) * 64 + sw * 16;
    const int boff = (wc * 64 + m) * 64 + sw * 16;

    // stage K-tile t32 (32 k, byte offset t32*64 in a KP-row) into ring buffer b
#define STAGE(t32_, b_) do {                                       \
        const int kb_ = (t32_) * 64;                               \
        char* a_  = AsW + (b_) * 8192;                             \
        char* bb_ = BsW + (b_) * 8192;                             \
        gld_lds16(Ag + kb_,             a_);                       \
        gld_lds16(Ag + kb_ + 64 * 2048, a_ + 4096);                \
        gld_lds16(Bg + kb_,             bb_);                      \
        gld_lds16(Bg + kb_ + 64 * 2048, bb_ + 4096);               \
    } while (0)

    STAGE(0, 0); STAGE(1, 1); STAGE(2, 2);       // 12 loads in flight per wave

    for (int t32 = 0; t32 < 32; ++t32) {
        const int b = t32 & 3;
        // own-wave contribution to buf b landed (4 loads/stage):
        if (t32 < 30)       asm volatile("s_waitcnt vmcnt(8)" ::: "memory");
        else if (t32 == 30) asm volatile("s_waitcnt vmcnt(4)" ::: "memory");
        else                asm volatile("s_waitcnt vmcnt(0)" ::: "memory");
        __builtin_amdgcn_s_barrier();            // now collectively ready
        const char* Ab = (const char*)As + b * 8192;
        const char* Bb = (const char*)Bs + b * 8192;
        bf16x8 af[4], bfv[4];
#pragma unroll
        for (int mt = 0; mt < 4; ++mt)
            af[mt] = *(const bf16x8*)(Ab + aoff + mt * 1024);
#pragma unroll
        for (int nt = 0; nt < 4; ++nt)
            bfv[nt] = *(const bf16x8*)(Bb + boff + nt * 1024);
#pragma unroll
        for (int mt = 0; mt < 4; ++mt)
#pragma unroll
            for (int nt = 0; nt < 4; ++nt)
                acc[mt][nt] = __builtin_amdgcn_mfma_f32_16x16x32_bf16(af[mt], bfv[nt], acc[mt][nt], 0, 0, 0);
        __builtin_amdgcn_s_barrier();            // all waves done reading buf b
        if (t32 + 3 < 32) STAGE(t32 + 3, (t32 + 3) & 3);   // overwrite b safely
    }
#undef STAGE

    // epilogue: C/D layout col = lane&15, row = quad*4 + reg
    const int col0 = tn * 128 + wc * 64 + m;
    const int row00 = tm * 128 + wr * 64 + quad * 4;
#pragma unroll
    for (int mt = 0; mt < 4; ++mt) {
        float ps0 = 0.f, ps1 = 0.f, ps2 = 0.f, ps3 = 0.f;
#pragma unroll
        for (int nt = 0; nt < 4; ++nt) {
            const int c = col0 + nt * 16;
            const float bbv = (c < 1000) ? b2[c] : 0.0f;
            const float wfv = (c < 1000) ? Wf[c] : 0.0f;
            ps0 += fmaxf(acc[mt][nt][0] + bbv, 0.f) * wfv;
            ps1 += fmaxf(acc[mt][nt][1] + bbv, 0.f) * wfv;
            ps2 += fmaxf(acc[mt][nt][2] + bbv, 0.f) * wfv;
            ps3 += fmaxf(acc[mt][nt][3] + bbv, 0.f) * wfv;
        }
#pragma unroll
        for (int msk = 1; msk < 16; msk <<= 1) {
            ps0 += __shfl_xor(ps0, msk);
            ps1 += __shfl_xor(ps1, msk);
            ps2 += __shfl_xor(ps2, msk);
            ps3 += __shfl_xor(ps3, msk);
        }
        if (m == 0) {
            const int row = row00 + mt * 16;
            if (row + 0 < nmv) atomicAdd(&logitsC[row + 0], ps0);
            if (row + 1 < nmv) atomicAdd(&logitsC[row + 1], ps1);
            if (row + 2 < nmv) atomicAdd(&logitsC[row + 2], ps2);
            if (row + 3 < nmv) atomicAdd(&logitsC[row + 3], ps3);
        }
    }
}

// segment softmax over compact (all-masked) logits; bc sorted -> binary search.
// out pre-zeroed by apply_kernel; only masked slots written via perm.
__global__ __launch_bounds__(256) void softmax_kernel(const float* __restrict__ logitsC,
        const int* __restrict__ perm, const int* __restrict__ bc,
        const int* __restrict__ nm, float* __restrict__ out) {
    const int g = blockIdx.x;
    const int t = threadIdx.x;
    __shared__ int s_lo, s_hi;
    __shared__ float red[4];
    __shared__ float sval;
    if (t == 0) {
        const int nmv = nm[0];
        int lo = 0, hi = nmv;
        while (lo < hi) { const int mid = (lo + hi) >> 1; if (bc[mid] < g) lo = mid + 1; else hi = mid; }
        s_lo = lo;
        int lo2 = lo, hi2 = nmv;
        while (lo2 < hi2) { const int mid = (lo2 + hi2) >> 1; if (bc[mid] < g + 1) lo2 = mid + 1; else hi2 = mid; }
        s_hi = lo2;
    }
    __syncthreads();
    const int lo = s_lo, hi = s_hi;
    float mx = -1e30f;
    for (int i = lo + t; i < hi; i += 256) mx = fmaxf(mx, logitsC[i]);
    for (int off = 32; off; off >>= 1) mx = fmaxf(mx, __shfl_down(mx, off));
    if ((t & 63) == 0) red[t >> 6] = mx;
    __syncthreads();
    if (t == 0) sval = fmaxf(fmaxf(red[0], red[1]), fmaxf(red[2], red[3]));
    __syncthreads();
    mx = sval;
    __syncthreads();
    float sm = 0.f;
    for (int i = lo + t; i < hi; i += 256) sm += expf(logitsC[i] - mx);
    for (int off = 32; off; off >>= 1) sm += __shfl_down(sm, off);
    if ((t & 63) == 0) red[t >> 6] = sm;
    __syncthreads();
    if (t == 0) sval = red[0] + red[1] + red[2] + red[3];
    __syncthreads();
    const float inv = 1.0f / fmaxf(sval, 1e-16f);
    for (int i = lo + t; i < hi; i += 256)
        out[perm[i]] = expf(logitsC[i] - mx) * inv;
}

extern "C" void kernel_launch(void* const* d_in, const int* in_sizes, int n_in,
                              void* d_out, int out_size, void* d_ws, size_t ws_size,
                              hipStream_t stream) {
    (void)in_sizes; (void)n_in; (void)out_size; (void)ws_size;
    const float* x   = (const float*)d_in[0];
    const float* ew  = (const float*)d_in[1];
    const float* W1  = (const float*)d_in[2];
    const float* b1  = (const float*)d_in[3];
    const float* W2  = (const float*)d_in[4];
    const float* b2  = (const float*)d_in[5];
    const float* Wf  = (const float*)d_in[6];
    const int*   ei  = (const int*)d_in[8];
    const void*  mask  = d_in[9];
    const int*   batch = (const int*)d_in[10];
    float* out = (float*)d_out;

    char* p = (char*)d_ws;
    auto carve = [&](size_t bytes) { char* q = p; p += (bytes + 255) & ~(size_t)255; return q; };
    // zero-region (single hipMemsetAsync): deg, cnt, flags only
    char* zbase = p;
    float* deg     = (float*)carve(NN * 4);
    int*   cnt     = (int*)carve(NN * 4);
    int*   flags   = (int*)carve(256);
    size_t zspan = (size_t)(p - zbase);
    int*   cursor  = (int*)carve(NN * 4);
    float* logitsC = (float*)carve(MPAD2 * 4);
    int*   offs   = (int*)carve(NN * 4);
    float* dinv   = (float*)carve(NN * 4);
    int*   mtmp   = (int*)carve(NN * 4);
    int*   perm   = (int*)carve(NN * 4);
    int*   bc     = (int*)carve(NN * 4);
    int*   bcnt   = (int*)carve(NBLK * 4);
    int*   bmsk   = (int*)carve(NBLK * 4);
    int*   nmp    = (int*)carve(256);
    int*   ssrc   = (int*)carve(NE * 4);
    float* snorm  = (float*)carve(NE * 4);
    float* Axf    = (float*)carve(NN * 5 * 4);
    unsigned short* W2t = (unsigned short*)carve((size_t)KP * KP * 2);
    unsigned short* G   = (unsigned short*)carve((size_t)MPAD2 * KP * 2);

    hipMemsetAsync(zbase, 0, zspan, stream);
    hipLaunchKernelGGL(deg_cnt_kernel,     dim3(625),       dim3(256), 0, stream, ei, ew, deg, cnt, mask, flags);
    hipLaunchKernelGGL(partial_w2t_kernel, dim3(NBLK+1024), dim3(256), 0, stream, cnt, deg, mask, flags, mtmp, dinv, bcnt, bmsk, W2, W2t, logitsC);
    hipLaunchKernelGGL(apply_kernel,       dim3(NBLK),      dim3(256), 0, stream, cnt, mtmp, bcnt, bmsk, batch, offs, perm, bc, nmp, cursor, out);
    hipLaunchKernelGGL(scatter_kernel,     dim3(625),       dim3(256), 0, stream, ei, ew, dinv, offs, cursor, ssrc, snorm);
    hipLaunchKernelGGL(axf_kernel,         dim3(79),        dim3(256), 0, stream, x, ssrc, snorm, offs, cnt, dinv, Axf);
    hipLaunchKernelGGL(aggW1_kernel,       dim3(MPAD2/8),   dim3(256), 0, stream, Axf, W1, b1, ssrc, snorm, offs, cnt, dinv, perm, nmp, G);
    hipLaunchKernelGGL(gemm_kernel,        dim3(MT2*8),     dim3(256), 0, stream, G, W2t, b2, Wf, nmp, logitsC);
    hipLaunchKernelGGL(softmax_kernel,     dim3(NG),        dim3(256), 0, stream, logitsC, perm, bc, nmp, out);
}

// Round 5
// 201.429 us; speedup vs baseline: 2.7839x; 1.0600x over previous
//
#include <hip/hip_runtime.h>

#define NN 20000
#define NE 160000
#define NG 16
#define KP 1024            // padded feature dim
#define MT2 160            // max M strips of 128 in compact space
#define MPAD2 (MT2*128)    // 20480
#define NBLK 79            // ceil(20000/256)

typedef __attribute__((ext_vector_type(8))) short bf16x8;
typedef __attribute__((ext_vector_type(4))) float f32x4;

#define GAS __attribute__((address_space(1)))
#define LAS __attribute__((address_space(3)))

__device__ __forceinline__ unsigned short f2bf(float f) {
    unsigned int u = __float_as_uint(f);
    u += 0x7FFFu + ((u >> 16) & 1u);   // round-to-nearest-even
    return (unsigned short)(u >> 16);
}

__device__ __forceinline__ void gld_lds16(const char* g, char* l) {
    __builtin_amdgcn_global_load_lds((GAS void*)g, (LAS void*)l, 16, 0, 0);
}

// deg/cnt/flags zeroed by hipMemsetAsync before this.
// Also probes the mask bit-format (int32 {0,1} / float32 {0,1.0f} / byte).
__global__ void deg_cnt_kernel(const int* __restrict__ ei, const float* __restrict__ ew,
                               float* deg, int* cnt, const void* __restrict__ mask,
                               int* flags) {
    const int e = blockIdx.x * blockDim.x + threadIdx.x;
    if (e < 5000) {
        const unsigned v = ((const unsigned*)mask)[e];
        if (v > 1u) atomicOr(&flags[0], 1);                      // not int32 {0,1}
        if (v != 0u && v != 0x3F800000u) atomicOr(&flags[1], 1); // not float32 {0,1.0f}
    }
    if (e >= NE) return;
    const int c = ei[NE + e];
    atomicAdd(&deg[c], ew[e]);
    atomicAdd(&cnt[c], 1);
}

// blocks 0..NBLK-1: per-block sums (edge counts + mask), dinv, mask decode.
// blocks NBLK..NBLK+1023: W2t[n][k] = bf16(W2[k][n]) zero-padded, + zero logitsC.
__global__ __launch_bounds__(256) void partial_w2t_kernel(const int* __restrict__ cnt,
        const float* __restrict__ deg, const void* __restrict__ mask,
        const int* __restrict__ flags, int* __restrict__ mtmp,
        float* __restrict__ dinv, int* __restrict__ bcnt, int* __restrict__ bmsk,
        const float* __restrict__ W2, unsigned short* __restrict__ W2t,
        float* __restrict__ logitsC) {
    const int bid = blockIdx.x;
    const int t = threadIdx.x;
    if (bid < NBLK) {
        const int i = bid * 256 + t;
        const int f0 = flags[0], f1 = flags[1];
        int c = 0, mv = 0;
        if (i < NN) {
            c = cnt[i];
            dinv[i] = 1.0f / sqrtf(2.0f + deg[i]);   // self-loop weight 2 folded; > 0
            if (f0 == 0)      mv = ((const int*)mask)[i] != 0;
            else if (f1 == 0) mv = ((const unsigned*)mask)[i] != 0u;
            else              mv = ((const unsigned char*)mask)[i] != 0;
            mtmp[i] = mv;
        }
        __shared__ int sc[256], sm[256];
        sc[t] = c; sm[t] = mv;
        __syncthreads();
        for (int off = 128; off; off >>= 1) {
            if (t < off) { sc[t] += sc[t + off]; sm[t] += sm[t + off]; }
            __syncthreads();
        }
        if (t == 0) { bcnt[bid] = sc[0]; bmsk[bid] = sm[0]; }
    } else {
        __shared__ float tile[32][33];
        const int bw = bid - NBLK;
        if (t < 20) logitsC[bw * 20 + t] = 0.0f;   // 1024*20 == 20480 == MPAD2
        const int n0 = (bw & 31) * 32;
        const int k0 = (bw >> 5) * 32;
        const int tx = t & 31, ty = t >> 5;        // 32 x 8
#pragma unroll
        for (int j = 0; j < 4; ++j) {
            const int k = k0 + ty + j * 8;
            const int n = n0 + tx;
            tile[ty + j * 8][tx] = (k < 1000 && n < 1000) ? W2[k * 1000 + n] : 0.0f;
        }
        __syncthreads();
#pragma unroll
        for (int j = 0; j < 4; ++j) {
            const int n = n0 + ty + j * 8;
            const int k = k0 + tx;
            W2t[(size_t)n * KP + k] = f2bf(tile[tx][ty + j * 8]);
        }
    }
}

// apply: re-scan the NBLK partials in-block, then in-block scan + offsets ->
// offs, perm, bc; block 0 writes nm. Also zeroes cursor (pre-scatter) and
// out (pre-softmax; unmasked slots must be 0).
__global__ __launch_bounds__(256) void apply_kernel(const int* __restrict__ cnt,
        const int* __restrict__ mtmp, const int* __restrict__ bcnt,
        const int* __restrict__ bmsk, const int* __restrict__ batch,
        int* __restrict__ offs, int* __restrict__ perm, int* __restrict__ bc,
        int* __restrict__ nm, int* __restrict__ cursor, float* __restrict__ out) {
    const int b = blockIdx.x, t = threadIdx.x;
    __shared__ int pbc[128], pbm[128];
    if (t < 128) {
        pbc[t] = (t < NBLK) ? bcnt[t] : 0;
        pbm[t] = (t < NBLK) ? bmsk[t] : 0;
    }
    __syncthreads();
    for (int off = 1; off < 128; off <<= 1) {       // inclusive scan of partials
        int uc = 0, um = 0;
        if (t < 128 && t >= off) { uc = pbc[t - off]; um = pbm[t - off]; }
        __syncthreads();
        if (t < 128) { pbc[t] += uc; pbm[t] += um; }
        __syncthreads();
    }
    if (b == 0 && t == 0) nm[0] = pbm[NBLK - 1];
    const int bco = (b == 0) ? 0 : pbc[b - 1];      // exclusive block offsets
    const int bmo = (b == 0) ? 0 : pbm[b - 1];
    const int i = b * 256 + t;
    const int c  = (i < NN) ? cnt[i]  : 0;
    const int mv = (i < NN) ? mtmp[i] : 0;
    __shared__ int sc[256], sm[256];
    sc[t] = c; sm[t] = mv;
    __syncthreads();
    for (int off = 1; off < 256; off <<= 1) {
        const int uc = (t >= off) ? sc[t - off] : 0;
        const int um = (t >= off) ? sm[t - off] : 0;
        __syncthreads();
        sc[t] += uc; sm[t] += um;
        __syncthreads();
    }
    if (i < NN) {
        cursor[i] = 0;
        out[i] = 0.0f;
        offs[i] = bco + sc[t] - c;                  // exclusive edge-count prefix
        if (mv) {
            const int pos = bmo + sm[t] - 1;        // compact slot
            perm[pos] = i;
            bc[pos] = batch[i];
        }
    }
}

__global__ void scatter_kernel(const int* __restrict__ ei, const float* __restrict__ ew,
                               const float* __restrict__ dinv, const int* __restrict__ offs,
                               int* cursor, int* __restrict__ ssrc, float* __restrict__ snorm) {
    const int e = blockIdx.x * blockDim.x + threadIdx.x;
    if (e >= NE) return;
    const int r = ei[e], c = ei[NE + e];
    const int pos = atomicAdd(&cursor[c], 1);
    const int idx = offs[c] + pos;
    ssrc[idx] = r;
    snorm[idx] = dinv[r] * ew[e] * dinv[c];
}

// Axf = full first-layer aggregation incl. self-loop
__global__ __launch_bounds__(256) void axf_kernel(const float* __restrict__ x,
        const int* __restrict__ ssrc, const float* __restrict__ snorm,
        const int* __restrict__ offs, const int* __restrict__ cnt,
        const float* __restrict__ dinv, float* __restrict__ Axf) {
    const int i = blockIdx.x * blockDim.x + threadIdx.x;
    if (i >= NN) return;
    float a0=0,a1=0,a2=0,a3=0,a4=0;
    const int s0 = offs[i], n = cnt[i];
    for (int e = s0; e < s0 + n; ++e) {
        const int r = ssrc[e];
        const float w = snorm[e];
        const float* xr = x + r * 5;
        a0 += w*xr[0]; a1 += w*xr[1]; a2 += w*xr[2]; a3 += w*xr[3]; a4 += w*xr[4];
    }
    const float wl = 2.0f * dinv[i] * dinv[i];
    const float* xi = x + i * 5;
    a0 += wl*xi[0]; a1 += wl*xi[1]; a2 += wl*xi[2]; a3 += wl*xi[3]; a4 += wl*xi[4];
    float* o = Axf + i * 5;
    o[0]=a0; o[1]=a1; o[2]=a2; o[3]=a3; o[4]=a4;
}

// G[j] = sum_e w_e * relu(Axf[src]@W1 + b1) — h1 never materialized. Barrier-free
// wave-pair structure (R11) + W1 AMORTIZATION (R12): each wave-pair owns 4
// consecutive dests, so the per-wave W1/b1 register fragment (10 KB/wave of L2
// traffic — the R11 residue, ~500 MB total at 2 dests/block) is loaded once per
// 4 dests (~50 MB total). Dest metadata prefetched in two batched rounds.
// Edge values broadcast via __shfl; no LDS, no __syncthreads.
__global__ __launch_bounds__(256) void aggW1_kernel(const float* __restrict__ Axf,
        const float* __restrict__ W1, const float* __restrict__ b1,
        const int* __restrict__ ssrc, const float* __restrict__ snorm,
        const int* __restrict__ offs, const int* __restrict__ cnt,
        const float* __restrict__ dinv, const int* __restrict__ perm,
        const int* __restrict__ nm, unsigned short* __restrict__ G) {
    const int tid = threadIdx.x;
    const int wv = tid >> 6;
    const int lane = tid & 63;
    const int half = wv & 1;
    const int jbase = blockIdx.x * 8 + (wv >> 1) * 4;   // wave-pair -> 4 dests
    const int nmv = nm[0];
    const int npad = (nmv + 127) & ~127;
    if (jbase >= npad) return;        // wave-uniform (no barriers in this kernel)

    const int c0 = half * 512 + lane * 8;
    float w1r[5][8], bbr[8];
#pragma unroll
    for (int q = 0; q < 2; ++q) {
        const int c = c0 + q * 4;
        const bool v = (c <= 996);    // 1000 % 4 == 0: quads are all-valid or all-pad
#pragma unroll
        for (int f = 0; f < 5; ++f) {
            const float4 w4 = v ? *(const float4*)(W1 + f * 1000 + c)
                                : make_float4(0.f, 0.f, 0.f, 0.f);
            w1r[f][q*4+0] = w4.x; w1r[f][q*4+1] = w4.y;
            w1r[f][q*4+2] = w4.z; w1r[f][q*4+3] = w4.w;
        }
        const float4 b4 = v ? *(const float4*)(b1 + c) : make_float4(0.f, 0.f, 0.f, 0.f);
        bbr[q*4+0] = b4.x; bbr[q*4+1] = b4.y; bbr[q*4+2] = b4.z; bbr[q*4+3] = b4.w;
    }

    // prefetch the 4 dests' metadata (two batched rounds -> latency pipelined)
    int iv[4], s0a[4], na[4]; float dva[4];
#pragma unroll
    for (int d = 0; d < 4; ++d) {
        const int j = jbase + d;                 // j < npad (npad is a mult of 8)
        iv[d] = (j < nmv) ? perm[j] : -1;
    }
#pragma unroll
    for (int d = 0; d < 4; ++d) {
        if (iv[d] >= 0) { s0a[d] = offs[iv[d]]; na[d] = cnt[iv[d]]; dva[d] = dinv[iv[d]]; }
        else            { s0a[d] = 0; na[d] = -1; dva[d] = 0.f; }
    }

#pragma unroll
    for (int d = 0; d < 4; ++d) {
        const int j = jbase + d;
        float acc[8];
#pragma unroll
        for (int k = 0; k < 8; ++k) acc[k] = 0.f;
        const int i = iv[d];
        if (i >= 0) {                            // wave-uniform
            const int s0 = s0a[d], n = na[d];
            const int total = n + 1;             // + self-loop pseudo-edge
            for (int base = 0; base < total; base += 64) {
                const int m = (total - base < 64) ? (total - base) : 64;
                float a0=0.f, a1=0.f, a2=0.f, a3=0.f, a4=0.f, we=0.f;
                if (lane < m) {
                    const int idx = base + lane;
                    int r;
                    if (idx < n) { r = ssrc[s0 + idx]; we = snorm[s0 + idx]; }
                    else         { r = i; we = 2.0f * dva[d] * dva[d]; }
                    const float* axr = Axf + r * 5;
                    a0 = axr[0]; a1 = axr[1]; a2 = axr[2]; a3 = axr[3]; a4 = axr[4];
                }
#pragma unroll 2
                for (int e = 0; e < m; ++e) {
                    const float s0v = __shfl(a0, e);
                    const float s1v = __shfl(a1, e);
                    const float s2v = __shfl(a2, e);
                    const float s3v = __shfl(a3, e);
                    const float s4v = __shfl(a4, e);
                    const float swv = __shfl(we, e);
#pragma unroll
                    for (int k = 0; k < 8; ++k) {
                        const float z = bbr[k] + s0v * w1r[0][k] + s1v * w1r[1][k]
                                      + s2v * w1r[2][k] + s3v * w1r[3][k] + s4v * w1r[4][k];
                        acc[k] += swv * fmaxf(z, 0.f);
                    }
                }
            }
        }
        bf16x8 pk;
#pragma unroll
        for (int k = 0; k < 8; ++k) pk[k] = (short)f2bf(acc[k]);
        *(bf16x8*)(G + (size_t)j * KP + c0) = pk;
    }
}

// logitsC[row] += sum_cols relu(G @ W2 + b2) * Wf over compact rows < nm.
// R17: 64x128 tile (was 128x128). R4 post-mortem: counted-vmcnt pipeline was
// NULL (49us, MfmaUtil 15%, occ 12%) -> bottleneck is OCCUPANCY-latency (2.5
// blocks/CU, barrier-coupled waves), not the vmcnt drain. Fix via TLP: halve
// BM -> 1264 active blocks (~5/CU, ~20 waves/CU), LDS 12.5KB, acc 32 VGPR.
// Simple 2-barrier loop (proven; pipelining null per R4/m99-m141). Same
// 16-row-block swizzle/fragment math as the verified 128x128 kernel.
// tm=(bid>>6)*8+(bid&7): strip's 8 tn-readers share an XCD (R6: FETCH 163->33MB).
__global__ __launch_bounds__(256) void gemm_kernel(const unsigned short* __restrict__ A,
                                                   const unsigned short* __restrict__ B,
                                                   const float* __restrict__ b2,
                                                   const float* __restrict__ Wf,
                                                   const int* __restrict__ nm,
                                                   float* __restrict__ logitsC) {
    __shared__ unsigned short As[2048];  // 64 rows x 32 k bf16 = 4 KB
    __shared__ unsigned short Bs[4096];  // 128 rows x 32 k bf16 = 8 KB
    const int tid = threadIdx.x;
    __shared__ int s_nm;
    if (tid == 0) s_nm = nm[0];
    __syncthreads();
    const int nmv = s_nm;
    const int mstrips = (nmv + 63) >> 6;         // 64-row strips
    const int bid = blockIdx.x;
    const int tm = (bid >> 6) * 8 + (bid & 7);   // 0..319, tm%8 == bid%8
    const int tn = (bid >> 3) & 7;
    if (tm >= mstrips) return;
    const int lane = tid & 63;
    const int wv = tid >> 6;
    const int wr = wv >> 1, wc = wv & 1;         // wave -> 32-row x 64-col quadrant

    const int chunk = ((tid & 3) ^ ((tid >> 3) & 3)) * 16;
    const int rsub = tid >> 2;                   // row 0..63
    const char* Ag = (const char*)(A + (size_t)(tm * 64 + rsub) * KP) + chunk;
    const char* Bg = (const char*)(B + (size_t)(tn * 128 + rsub) * KP) + chunk;
    char* AsW = (char*)As + wv * 1024;           // wave stages rows 16w..16w+15
    char* BsW = (char*)Bs + wv * 1024;

    f32x4 acc[2][4];
#pragma unroll
    for (int i = 0; i < 2; ++i)
#pragma unroll
        for (int j = 0; j < 4; ++j) acc[i][j] = (f32x4){0.f, 0.f, 0.f, 0.f};

    const int m = lane & 15;
    const int quad = lane >> 4;
    const int sw = quad ^ ((m >> 1) & 3);        // swizzled k-chunk slot
    const int aoff = (wr * 32 + m) * 64 + sw * 16;
    const int boff = (wc * 64 + m) * 64 + sw * 16;

    for (int kk = 0; kk < KP; kk += 32) {
        __syncthreads();
        const int kb = kk * 2;
        gld_lds16(Ag + kb,             AsW);          // A: 4KB total (1 gld/wave)
        gld_lds16(Bg + kb,             BsW);          // B rows 0..63
        gld_lds16(Bg + kb + 64 * 2048, BsW + 4096);   // B rows 64..127
        __syncthreads();
        bf16x8 af[2], bfv[4];
#pragma unroll
        for (int mt = 0; mt < 2; ++mt)
            af[mt] = *(const bf16x8*)((const char*)As + aoff + mt * 1024);
#pragma unroll
        for (int nt = 0; nt < 4; ++nt)
            bfv[nt] = *(const bf16x8*)((const char*)Bs + boff + nt * 1024);
#pragma unroll
        for (int mt = 0; mt < 2; ++mt)
#pragma unroll
            for (int nt = 0; nt < 4; ++nt)
                acc[mt][nt] = __builtin_amdgcn_mfma_f32_16x16x32_bf16(af[mt], bfv[nt], acc[mt][nt], 0, 0, 0);
    }

    // epilogue: C/D layout col = lane&15, row = quad*4 + reg
    const int col0 = tn * 128 + wc * 64 + m;
    const int row00 = tm * 64 + wr * 32 + quad * 4;
#pragma unroll
    for (int mt = 0; mt < 2; ++mt) {
        float ps0 = 0.f, ps1 = 0.f, ps2 = 0.f, ps3 = 0.f;
#pragma unroll
        for (int nt = 0; nt < 4; ++nt) {
            const int c = col0 + nt * 16;
            const float bbv = (c < 1000) ? b2[c] : 0.0f;
            const float wfv = (c < 1000) ? Wf[c] : 0.0f;
            ps0 += fmaxf(acc[mt][nt][0] + bbv, 0.f) * wfv;
            ps1 += fmaxf(acc[mt][nt][1] + bbv, 0.f) * wfv;
            ps2 += fmaxf(acc[mt][nt][2] + bbv, 0.f) * wfv;
            ps3 += fmaxf(acc[mt][nt][3] + bbv, 0.f) * wfv;
        }
#pragma unroll
        for (int msk = 1; msk < 16; msk <<= 1) {
            ps0 += __shfl_xor(ps0, msk);
            ps1 += __shfl_xor(ps1, msk);
            ps2 += __shfl_xor(ps2, msk);
            ps3 += __shfl_xor(ps3, msk);
        }
        if (m == 0) {
            const int row = row00 + mt * 16;
            if (row + 0 < nmv) atomicAdd(&logitsC[row + 0], ps0);
            if (row + 1 < nmv) atomicAdd(&logitsC[row + 1], ps1);
            if (row + 2 < nmv) atomicAdd(&logitsC[row + 2], ps2);
            if (row + 3 < nmv) atomicAdd(&logitsC[row + 3], ps3);
        }
    }
}

// segment softmax over compact (all-masked) logits; bc sorted -> binary search.
// out pre-zeroed by apply_kernel; only masked slots written via perm.
__global__ __launch_bounds__(256) void softmax_kernel(const float* __restrict__ logitsC,
        const int* __restrict__ perm, const int* __restrict__ bc,
        const int* __restrict__ nm, float* __restrict__ out) {
    const int g = blockIdx.x;
    const int t = threadIdx.x;
    __shared__ int s_lo, s_hi;
    __shared__ float red[4];
    __shared__ float sval;
    if (t == 0) {
        const int nmv = nm[0];
        int lo = 0, hi = nmv;
        while (lo < hi) { const int mid = (lo + hi) >> 1; if (bc[mid] < g) lo = mid + 1; else hi = mid; }
        s_lo = lo;
        int lo2 = lo, hi2 = nmv;
        while (lo2 < hi2) { const int mid = (lo2 + hi2) >> 1; if (bc[mid] < g + 1) lo2 = mid + 1; else hi2 = mid; }
        s_hi = lo2;
    }
    __syncthreads();
    const int lo = s_lo, hi = s_hi;
    float mx = -1e30f;
    for (int i = lo + t; i < hi; i += 256) mx = fmaxf(mx, logitsC[i]);
    for (int off = 32; off; off >>= 1) mx = fmaxf(mx, __shfl_down(mx, off));
    if ((t & 63) == 0) red[t >> 6] = mx;
    __syncthreads();
    if (t == 0) sval = fmaxf(fmaxf(red[0], red[1]), fmaxf(red[2], red[3]));
    __syncthreads();
    mx = sval;
    __syncthreads();
    float sm = 0.f;
    for (int i = lo + t; i < hi; i += 256) sm += expf(logitsC[i] - mx);
    for (int off = 32; off; off >>= 1) sm += __shfl_down(sm, off);
    if ((t & 63) == 0) red[t >> 6] = sm;
    __syncthreads();
    if (t == 0) sval = red[0] + red[1] + red[2] + red[3];
    __syncthreads();
    const float inv = 1.0f / fmaxf(sval, 1e-16f);
    for (int i = lo + t; i < hi; i += 256)
        out[perm[i]] = expf(logitsC[i] - mx) * inv;
}

extern "C" void kernel_launch(void* const* d_in, const int* in_sizes, int n_in,
                              void* d_out, int out_size, void* d_ws, size_t ws_size,
                              hipStream_t stream) {
    (void)in_sizes; (void)n_in; (void)out_size; (void)ws_size;
    const float* x   = (const float*)d_in[0];
    const float* ew  = (const float*)d_in[1];
    const float* W1  = (const float*)d_in[2];
    const float* b1  = (const float*)d_in[3];
    const float* W2  = (const float*)d_in[4];
    const float* b2  = (const float*)d_in[5];
    const float* Wf  = (const float*)d_in[6];
    const int*   ei  = (const int*)d_in[8];
    const void*  mask  = d_in[9];
    const int*   batch = (const int*)d_in[10];
    float* out = (float*)d_out;

    char* p = (char*)d_ws;
    auto carve = [&](size_t bytes) { char* q = p; p += (bytes + 255) & ~(size_t)255; return q; };
    // zero-region (single hipMemsetAsync): deg, cnt, flags only
    char* zbase = p;
    float* deg     = (float*)carve(NN * 4);
    int*   cnt     = (int*)carve(NN * 4);
    int*   flags   = (int*)carve(256);
    size_t zspan = (size_t)(p - zbase);
    int*   cursor  = (int*)carve(NN * 4);
    float* logitsC = (float*)carve(MPAD2 * 4);
    int*   offs   = (int*)carve(NN * 4);
    float* dinv   = (float*)carve(NN * 4);
    int*   mtmp   = (int*)carve(NN * 4);
    int*   perm   = (int*)carve(NN * 4);
    int*   bc     = (int*)carve(NN * 4);
    int*   bcnt   = (int*)carve(NBLK * 4);
    int*   bmsk   = (int*)carve(NBLK * 4);
    int*   nmp    = (int*)carve(256);
    int*   ssrc   = (int*)carve(NE * 4);
    float* snorm  = (float*)carve(NE * 4);
    float* Axf    = (float*)carve(NN * 5 * 4);
    unsigned short* W2t = (unsigned short*)carve((size_t)KP * KP * 2);
    unsigned short* G   = (unsigned short*)carve((size_t)MPAD2 * KP * 2);

    hipMemsetAsync(zbase, 0, zspan, stream);
    hipLaunchKernelGGL(deg_cnt_kernel,     dim3(625),       dim3(256), 0, stream, ei, ew, deg, cnt, mask, flags);
    hipLaunchKernelGGL(partial_w2t_kernel, dim3(NBLK+1024), dim3(256), 0, stream, cnt, deg, mask, flags, mtmp, dinv, bcnt, bmsk, W2, W2t, logitsC);
    hipLaunchKernelGGL(apply_kernel,       dim3(NBLK),      dim3(256), 0, stream, cnt, mtmp, bcnt, bmsk, batch, offs, perm, bc, nmp, cursor, out);
    hipLaunchKernelGGL(scatter_kernel,     dim3(625),       dim3(256), 0, stream, ei, ew, dinv, offs, cursor, ssrc, snorm);
    hipLaunchKernelGGL(axf_kernel,         dim3(79),        dim3(256), 0, stream, x, ssrc, snorm, offs, cnt, dinv, Axf);
    hipLaunchKernelGGL(aggW1_kernel,       dim3(MPAD2/8),   dim3(256), 0, stream, Axf, W1, b1, ssrc, snorm, offs, cnt, dinv, perm, nmp, G);
    hipLaunchKernelGGL(gemm_kernel,        dim3(MPAD2/64*8),dim3(256), 0, stream, G, W2t, b2, Wf, nmp, logitsC);
    hipLaunchKernelGGL(softmax_kernel,     dim3(NG),        dim3(256), 0, stream, logitsC, perm, bc, nmp, out);
}

// Round 6
// 199.035 us; speedup vs baseline: 2.8173x; 1.0120x over previous
//
#include <hip/hip_runtime.h>

#define NN 20000
#define NE 160000
#define NG 16
#define KP 1024            // padded feature dim
#define MT2 160            // max M strips of 128 in compact space
#define MPAD2 (MT2*128)    // 20480
#define NBLK 79            // ceil(20000/256)

typedef __attribute__((ext_vector_type(8))) short bf16x8;
typedef __attribute__((ext_vector_type(4))) float f32x4;

#define GAS __attribute__((address_space(1)))
#define LAS __attribute__((address_space(3)))

__device__ __forceinline__ unsigned short f2bf(float f) {
    unsigned int u = __float_as_uint(f);
    u += 0x7FFFu + ((u >> 16) & 1u);   // round-to-nearest-even
    return (unsigned short)(u >> 16);
}

__device__ __forceinline__ void gld_lds16(const char* g, char* l) {
    __builtin_amdgcn_global_load_lds((GAS void*)g, (LAS void*)l, 16, 0, 0);
}

// R18: 4-way REPLICATED deg/cnt (rep = blockIdx&3) — R5 model: 640K device
// atomics on 624 cache lines (~512 serialized ops/line) dominate this kernel.
// Replication cuts per-line contention 4x. The cnt atomicAdd's RETURN VALUE is
// stored as rank[e] (free) -> scatter needs NO atomics at all.
// deg_r/cnt_r/flags zeroed by hipMemsetAsync before this.
__global__ void deg_cnt_kernel(const int* __restrict__ ei, const float* __restrict__ ew,
                               const void* __restrict__ mask, float* deg_r, int* cnt_r,
                               int* flags, int* __restrict__ rank) {
    const int e = blockIdx.x * blockDim.x + threadIdx.x;
    if (e < 5000) {
        const unsigned v = ((const unsigned*)mask)[e];
        if (v > 1u) atomicOr(&flags[0], 1);                      // not int32 {0,1}
        if (v != 0u && v != 0x3F800000u) atomicOr(&flags[1], 1); // not float32 {0,1.0f}
    }
    if (e >= NE) return;
    const int rep = blockIdx.x & 3;
    const int c = ei[NE + e];
    atomicAdd(&deg_r[rep * NN + c], ew[e]);
    rank[e] = atomicAdd(&cnt_r[rep * NN + c], 1);   // rank within (rep, c)
}

// blocks 0..NBLK-1: reduce the 4 replicas -> cnt total + per-replica exclusive
// offsets repoff[4][NN] (for rank-based scatter), dinv, mask decode, per-block
// sums for the scan. blocks NBLK..: W2t transpose + logitsC zero (unchanged).
__global__ __launch_bounds__(256) void partial_w2t_kernel(const int* __restrict__ cnt_r,
        const float* __restrict__ deg_r, const void* __restrict__ mask,
        const int* __restrict__ flags, int* __restrict__ mtmp,
        float* __restrict__ dinv, int* __restrict__ cnt, int* __restrict__ repoff,
        int* __restrict__ bcnt, int* __restrict__ bmsk,
        const float* __restrict__ W2, unsigned short* __restrict__ W2t,
        float* __restrict__ logitsC) {
    const int bid = blockIdx.x;
    const int t = threadIdx.x;
    if (bid < NBLK) {
        const int i = bid * 256 + t;
        const int f0 = flags[0], f1 = flags[1];
        int c = 0, mv = 0;
        if (i < NN) {
            const int c0 = cnt_r[i],          c1 = cnt_r[NN + i];
            const int c2 = cnt_r[2 * NN + i], c3 = cnt_r[3 * NN + i];
            c = c0 + c1 + c2 + c3;
            cnt[i] = c;
            repoff[i]          = 0;
            repoff[NN + i]     = c0;
            repoff[2 * NN + i] = c0 + c1;
            repoff[3 * NN + i] = c0 + c1 + c2;
            const float d = deg_r[i] + deg_r[NN + i] + deg_r[2 * NN + i] + deg_r[3 * NN + i];
            dinv[i] = 1.0f / sqrtf(2.0f + d);   // self-loop weight 2 folded; > 0
            if (f0 == 0)      mv = ((const int*)mask)[i] != 0;
            else if (f1 == 0) mv = ((const unsigned*)mask)[i] != 0u;
            else              mv = ((const unsigned char*)mask)[i] != 0;
            mtmp[i] = mv;
        }
        __shared__ int sc[256], sm[256];
        sc[t] = c; sm[t] = mv;
        __syncthreads();
        for (int off = 128; off; off >>= 1) {
            if (t < off) { sc[t] += sc[t + off]; sm[t] += sm[t + off]; }
            __syncthreads();
        }
        if (t == 0) { bcnt[bid] = sc[0]; bmsk[bid] = sm[0]; }
    } else {
        __shared__ float tile[32][33];
        const int bw = bid - NBLK;
        if (t < 20) logitsC[bw * 20 + t] = 0.0f;   // 1024*20 == 20480 == MPAD2
        const int n0 = (bw & 31) * 32;
        const int k0 = (bw >> 5) * 32;
        const int tx = t & 31, ty = t >> 5;        // 32 x 8
#pragma unroll
        for (int j = 0; j < 4; ++j) {
            const int k = k0 + ty + j * 8;
            const int n = n0 + tx;
            tile[ty + j * 8][tx] = (k < 1000 && n < 1000) ? W2[k * 1000 + n] : 0.0f;
        }
        __syncthreads();
#pragma unroll
        for (int j = 0; j < 4; ++j) {
            const int n = n0 + ty + j * 8;
            const int k = k0 + tx;
            W2t[(size_t)n * KP + k] = f2bf(tile[tx][ty + j * 8]);
        }
    }
}

// apply: re-scan the NBLK partials in-block, then in-block scan + offsets ->
// offs, perm, bc; block 0 writes nm. Also zeroes out (pre-softmax; unmasked
// slots must be 0). cursor is GONE (rank-based scatter needs no atomics).
__global__ __launch_bounds__(256) void apply_kernel(const int* __restrict__ cnt,
        const int* __restrict__ mtmp, const int* __restrict__ bcnt,
        const int* __restrict__ bmsk, const int* __restrict__ batch,
        int* __restrict__ offs, int* __restrict__ perm, int* __restrict__ bc,
        int* __restrict__ nm, float* __restrict__ out) {
    const int b = blockIdx.x, t = threadIdx.x;
    __shared__ int pbc[128], pbm[128];
    if (t < 128) {
        pbc[t] = (t < NBLK) ? bcnt[t] : 0;
        pbm[t] = (t < NBLK) ? bmsk[t] : 0;
    }
    __syncthreads();
    for (int off = 1; off < 128; off <<= 1) {       // inclusive scan of partials
        int uc = 0, um = 0;
        if (t < 128 && t >= off) { uc = pbc[t - off]; um = pbm[t - off]; }
        __syncthreads();
        if (t < 128) { pbc[t] += uc; pbm[t] += um; }
        __syncthreads();
    }
    if (b == 0 && t == 0) nm[0] = pbm[NBLK - 1];
    const int bco = (b == 0) ? 0 : pbc[b - 1];      // exclusive block offsets
    const int bmo = (b == 0) ? 0 : pbm[b - 1];
    const int i = b * 256 + t;
    const int c  = (i < NN) ? cnt[i]  : 0;
    const int mv = (i < NN) ? mtmp[i] : 0;
    __shared__ int sc[256], sm[256];
    sc[t] = c; sm[t] = mv;
    __syncthreads();
    for (int off = 1; off < 256; off <<= 1) {
        const int uc = (t >= off) ? sc[t - off] : 0;
        const int um = (t >= off) ? sm[t - off] : 0;
        __syncthreads();
        sc[t] += uc; sm[t] += um;
        __syncthreads();
    }
    if (i < NN) {
        out[i] = 0.0f;
        offs[i] = bco + sc[t] - c;                  // exclusive edge-count prefix
        if (mv) {
            const int pos = bmo + sm[t] - 1;        // compact slot
            perm[pos] = i;
            bc[pos] = batch[i];
        }
    }
}

// R18 scatter: ATOMIC-FREE. Slot = offs[c] + repoff[rep][c] + rank[e] where
// rep = (e>>8)&3 matches deg_cnt's blockIdx&3 (same 625x256 grid). rank[e] is
// coalesced; offs/repoff are L2-hot gathers.
__global__ void scatter_kernel(const int* __restrict__ ei, const float* __restrict__ ew,
                               const float* __restrict__ dinv, const int* __restrict__ offs,
                               const int* __restrict__ repoff, const int* __restrict__ rank,
                               int* __restrict__ ssrc, float* __restrict__ snorm) {
    const int e = blockIdx.x * blockDim.x + threadIdx.x;
    if (e >= NE) return;
    const int r = ei[e], c = ei[NE + e];
    const int rep = (e >> 8) & 3;
    const int idx = offs[c] + repoff[rep * NN + c] + rank[e];
    ssrc[idx] = r;
    snorm[idx] = dinv[r] * ew[e] * dinv[c];
}

// Axf = full first-layer aggregation incl. self-loop
__global__ __launch_bounds__(256) void axf_kernel(const float* __restrict__ x,
        const int* __restrict__ ssrc, const float* __restrict__ snorm,
        const int* __restrict__ offs, const int* __restrict__ cnt,
        const float* __restrict__ dinv, float* __restrict__ Axf) {
    const int i = blockIdx.x * blockDim.x + threadIdx.x;
    if (i >= NN) return;
    float a0=0,a1=0,a2=0,a3=0,a4=0;
    const int s0 = offs[i], n = cnt[i];
    for (int e = s0; e < s0 + n; ++e) {
        const int r = ssrc[e];
        const float w = snorm[e];
        const float* xr = x + r * 5;
        a0 += w*xr[0]; a1 += w*xr[1]; a2 += w*xr[2]; a3 += w*xr[3]; a4 += w*xr[4];
    }
    const float wl = 2.0f * dinv[i] * dinv[i];
    const float* xi = x + i * 5;
    a0 += wl*xi[0]; a1 += wl*xi[1]; a2 += wl*xi[2]; a3 += wl*xi[3]; a4 += wl*xi[4];
    float* o = Axf + i * 5;
    o[0]=a0; o[1]=a1; o[2]=a2; o[3]=a3; o[4]=a4;
}

// G[j] = sum_e w_e * relu(Axf[src]@W1 + b1) — h1 never materialized. Barrier-free
// wave-pair structure (R11) + W1 AMORTIZATION (R12): each wave-pair owns 4
// consecutive dests, so the per-wave W1/b1 register fragment is loaded once per
// 4 dests. Dest metadata prefetched in two batched rounds.
// Edge values broadcast via __shfl; no LDS, no __syncthreads.
__global__ __launch_bounds__(256) void aggW1_kernel(const float* __restrict__ Axf,
        const float* __restrict__ W1, const float* __restrict__ b1,
        const int* __restrict__ ssrc, const float* __restrict__ snorm,
        const int* __restrict__ offs, const int* __restrict__ cnt,
        const float* __restrict__ dinv, const int* __restrict__ perm,
        const int* __restrict__ nm, unsigned short* __restrict__ G) {
    const int tid = threadIdx.x;
    const int wv = tid >> 6;
    const int lane = tid & 63;
    const int half = wv & 1;
    const int jbase = blockIdx.x * 8 + (wv >> 1) * 4;   // wave-pair -> 4 dests
    const int nmv = nm[0];
    const int npad = (nmv + 127) & ~127;
    if (jbase >= npad) return;        // wave-uniform (no barriers in this kernel)

    const int c0 = half * 512 + lane * 8;
    float w1r[5][8], bbr[8];
#pragma unroll
    for (int q = 0; q < 2; ++q) {
        const int c = c0 + q * 4;
        const bool v = (c <= 996);    // 1000 % 4 == 0: quads are all-valid or all-pad
#pragma unroll
        for (int f = 0; f < 5; ++f) {
            const float4 w4 = v ? *(const float4*)(W1 + f * 1000 + c)
                                : make_float4(0.f, 0.f, 0.f, 0.f);
            w1r[f][q*4+0] = w4.x; w1r[f][q*4+1] = w4.y;
            w1r[f][q*4+2] = w4.z; w1r[f][q*4+3] = w4.w;
        }
        const float4 b4 = v ? *(const float4*)(b1 + c) : make_float4(0.f, 0.f, 0.f, 0.f);
        bbr[q*4+0] = b4.x; bbr[q*4+1] = b4.y; bbr[q*4+2] = b4.z; bbr[q*4+3] = b4.w;
    }

    // prefetch the 4 dests' metadata (two batched rounds -> latency pipelined)
    int iv[4], s0a[4], na[4]; float dva[4];
#pragma unroll
    for (int d = 0; d < 4; ++d) {
        const int j = jbase + d;                 // j < npad (npad is a mult of 8)
        iv[d] = (j < nmv) ? perm[j] : -1;
    }
#pragma unroll
    for (int d = 0; d < 4; ++d) {
        if (iv[d] >= 0) { s0a[d] = offs[iv[d]]; na[d] = cnt[iv[d]]; dva[d] = dinv[iv[d]]; }
        else            { s0a[d] = 0; na[d] = -1; dva[d] = 0.f; }
    }

#pragma unroll
    for (int d = 0; d < 4; ++d) {
        const int j = jbase + d;
        float acc[8];
#pragma unroll
        for (int k = 0; k < 8; ++k) acc[k] = 0.f;
        const int i = iv[d];
        if (i >= 0) {                            // wave-uniform
            const int s0 = s0a[d], n = na[d];
            const int total = n + 1;             // + self-loop pseudo-edge
            for (int base = 0; base < total; base += 64) {
                const int m = (total - base < 64) ? (total - base) : 64;
                float a0=0.f, a1=0.f, a2=0.f, a3=0.f, a4=0.f, we=0.f;
                if (lane < m) {
                    const int idx = base + lane;
                    int r;
                    if (idx < n) { r = ssrc[s0 + idx]; we = snorm[s0 + idx]; }
                    else         { r = i; we = 2.0f * dva[d] * dva[d]; }
                    const float* axr = Axf + r * 5;
                    a0 = axr[0]; a1 = axr[1]; a2 = axr[2]; a3 = axr[3]; a4 = axr[4];
                }
#pragma unroll 2
                for (int e = 0; e < m; ++e) {
                    const float s0v = __shfl(a0, e);
                    const float s1v = __shfl(a1, e);
                    const float s2v = __shfl(a2, e);
                    const float s3v = __shfl(a3, e);
                    const float s4v = __shfl(a4, e);
                    const float swv = __shfl(we, e);
#pragma unroll
                    for (int k = 0; k < 8; ++k) {
                        const float z = bbr[k] + s0v * w1r[0][k] + s1v * w1r[1][k]
                                      + s2v * w1r[2][k] + s3v * w1r[3][k] + s4v * w1r[4][k];
                        acc[k] += swv * fmaxf(z, 0.f);
                    }
                }
            }
        }
        bf16x8 pk;
#pragma unroll
        for (int k = 0; k < 8; ++k) pk[k] = (short)f2bf(acc[k]);
        *(bf16x8*)(G + (size_t)j * KP + c0) = pk;
    }
}

// logitsC[row] += sum_cols relu(G @ W2 + b2) * Wf over compact rows < nm.
// R17 64x128 tile (kept from R5): ~1264 active blocks (~5/CU), simple 2-barrier
// loop. R5 post-mortem: this shape (M~10K, K=1024) plateaus ~37us across all
// 2-barrier structural variants (BK64=45, vmcnt-ring=49, 64x128=~37) — frozen.
// tm=(bid>>6)*8+(bid&7): strip's 8 tn-readers share an XCD (R6: FETCH 163->33MB).
__global__ __launch_bounds__(256) void gemm_kernel(const unsigned short* __restrict__ A,
                                                   const unsigned short* __restrict__ B,
                                                   const float* __restrict__ b2,
                                                   const float* __restrict__ Wf,
                                                   const int* __restrict__ nm,
                                                   float* __restrict__ logitsC) {
    __shared__ unsigned short As[2048];  // 64 rows x 32 k bf16 = 4 KB
    __shared__ unsigned short Bs[4096];  // 128 rows x 32 k bf16 = 8 KB
    const int tid = threadIdx.x;
    __shared__ int s_nm;
    if (tid == 0) s_nm = nm[0];
    __syncthreads();
    const int nmv = s_nm;
    const int mstrips = (nmv + 63) >> 6;         // 64-row strips
    const int bid = blockIdx.x;
    const int tm = (bid >> 6) * 8 + (bid & 7);   // 0..319, tm%8 == bid%8
    const int tn = (bid >> 3) & 7;
    if (tm >= mstrips) return;
    const int lane = tid & 63;
    const int wv = tid >> 6;
    const int wr = wv >> 1, wc = wv & 1;         // wave -> 32-row x 64-col quadrant

    const int chunk = ((tid & 3) ^ ((tid >> 3) & 3)) * 16;
    const int rsub = tid >> 2;                   // row 0..63
    const char* Ag = (const char*)(A + (size_t)(tm * 64 + rsub) * KP) + chunk;
    const char* Bg = (const char*)(B + (size_t)(tn * 128 + rsub) * KP) + chunk;
    char* AsW = (char*)As + wv * 1024;           // wave stages rows 16w..16w+15
    char* BsW = (char*)Bs + wv * 1024;

    f32x4 acc[2][4];
#pragma unroll
    for (int i = 0; i < 2; ++i)
#pragma unroll
        for (int j = 0; j < 4; ++j) acc[i][j] = (f32x4){0.f, 0.f, 0.f, 0.f};

    const int m = lane & 15;
    const int quad = lane >> 4;
    const int sw = quad ^ ((m >> 1) & 3);        // swizzled k-chunk slot
    const int aoff = (wr * 32 + m) * 64 + sw * 16;
    const int boff = (wc * 64 + m) * 64 + sw * 16;

    for (int kk = 0; kk < KP; kk += 32) {
        __syncthreads();
        const int kb = kk * 2;
        gld_lds16(Ag + kb,             AsW);          // A: 4KB total (1 gld/wave)
        gld_lds16(Bg + kb,             BsW);          // B rows 0..63
        gld_lds16(Bg + kb + 64 * 2048, BsW + 4096);   // B rows 64..127
        __syncthreads();
        bf16x8 af[2], bfv[4];
#pragma unroll
        for (int mt = 0; mt < 2; ++mt)
            af[mt] = *(const bf16x8*)((const char*)As + aoff + mt * 1024);
#pragma unroll
        for (int nt = 0; nt < 4; ++nt)
            bfv[nt] = *(const bf16x8*)((const char*)Bs + boff + nt * 1024);
#pragma unroll
        for (int mt = 0; mt < 2; ++mt)
#pragma unroll
            for (int nt = 0; nt < 4; ++nt)
                acc[mt][nt] = __builtin_amdgcn_mfma_f32_16x16x32_bf16(af[mt], bfv[nt], acc[mt][nt], 0, 0, 0);
    }

    // epilogue: C/D layout col = lane&15, row = quad*4 + reg
    const int col0 = tn * 128 + wc * 64 + m;
    const int row00 = tm * 64 + wr * 32 + quad * 4;
#pragma unroll
    for (int mt = 0; mt < 2; ++mt) {
        float ps0 = 0.f, ps1 = 0.f, ps2 = 0.f, ps3 = 0.f;
#pragma unroll
        for (int nt = 0; nt < 4; ++nt) {
            const int c = col0 + nt * 16;
            const float bbv = (c < 1000) ? b2[c] : 0.0f;
            const float wfv = (c < 1000) ? Wf[c] : 0.0f;
            ps0 += fmaxf(acc[mt][nt][0] + bbv, 0.f) * wfv;
            ps1 += fmaxf(acc[mt][nt][1] + bbv, 0.f) * wfv;
            ps2 += fmaxf(acc[mt][nt][2] + bbv, 0.f) * wfv;
            ps3 += fmaxf(acc[mt][nt][3] + bbv, 0.f) * wfv;
        }
#pragma unroll
        for (int msk = 1; msk < 16; msk <<= 1) {
            ps0 += __shfl_xor(ps0, msk);
            ps1 += __shfl_xor(ps1, msk);
            ps2 += __shfl_xor(ps2, msk);
            ps3 += __shfl_xor(ps3, msk);
        }
        if (m == 0) {
            const int row = row00 + mt * 16;
            if (row + 0 < nmv) atomicAdd(&logitsC[row + 0], ps0);
            if (row + 1 < nmv) atomicAdd(&logitsC[row + 1], ps1);
            if (row + 2 < nmv) atomicAdd(&logitsC[row + 2], ps2);
            if (row + 3 < nmv) atomicAdd(&logitsC[row + 3], ps3);
        }
    }
}

// segment softmax over compact (all-masked) logits; bc sorted -> binary search.
// out pre-zeroed by apply_kernel; only masked slots written via perm.
__global__ __launch_bounds__(256) void softmax_kernel(const float* __restrict__ logitsC,
        const int* __restrict__ perm, const int* __restrict__ bc,
        const int* __restrict__ nm, float* __restrict__ out) {
    const int g = blockIdx.x;
    const int t = threadIdx.x;
    __shared__ int s_lo, s_hi;
    __shared__ float red[4];
    __shared__ float sval;
    if (t == 0) {
        const int nmv = nm[0];
        int lo = 0, hi = nmv;
        while (lo < hi) { const int mid = (lo + hi) >> 1; if (bc[mid] < g) lo = mid + 1; else hi = mid; }
        s_lo = lo;
        int lo2 = lo, hi2 = nmv;
        while (lo2 < hi2) { const int mid = (lo2 + hi2) >> 1; if (bc[mid] < g + 1) lo2 = mid + 1; else hi2 = mid; }
        s_hi = lo2;
    }
    __syncthreads();
    const int lo = s_lo, hi = s_hi;
    float mx = -1e30f;
    for (int i = lo + t; i < hi; i += 256) mx = fmaxf(mx, logitsC[i]);
    for (int off = 32; off; off >>= 1) mx = fmaxf(mx, __shfl_down(mx, off));
    if ((t & 63) == 0) red[t >> 6] = mx;
    __syncthreads();
    if (t == 0) sval = fmaxf(fmaxf(red[0], red[1]), fmaxf(red[2], red[3]));
    __syncthreads();
    mx = sval;
    __syncthreads();
    float sm = 0.f;
    for (int i = lo + t; i < hi; i += 256) sm += expf(logitsC[i] - mx);
    for (int off = 32; off; off >>= 1) sm += __shfl_down(sm, off);
    if ((t & 63) == 0) red[t >> 6] = sm;
    __syncthreads();
    if (t == 0) sval = red[0] + red[1] + red[2] + red[3];
    __syncthreads();
    const float inv = 1.0f / fmaxf(sval, 1e-16f);
    for (int i = lo + t; i < hi; i += 256)
        out[perm[i]] = expf(logitsC[i] - mx) * inv;
}

extern "C" void kernel_launch(void* const* d_in, const int* in_sizes, int n_in,
                              void* d_out, int out_size, void* d_ws, size_t ws_size,
                              hipStream_t stream) {
    (void)in_sizes; (void)n_in; (void)out_size; (void)ws_size;
    const float* x   = (const float*)d_in[0];
    const float* ew  = (const float*)d_in[1];
    const float* W1  = (const float*)d_in[2];
    const float* b1  = (const float*)d_in[3];
    const float* W2  = (const float*)d_in[4];
    const float* b2  = (const float*)d_in[5];
    const float* Wf  = (const float*)d_in[6];
    const int*   ei  = (const int*)d_in[8];
    const void*  mask  = d_in[9];
    const int*   batch = (const int*)d_in[10];
    float* out = (float*)d_out;

    char* p = (char*)d_ws;
    auto carve = [&](size_t bytes) { char* q = p; p += (bytes + 255) & ~(size_t)255; return q; };
    // zero-region (single hipMemsetAsync): deg_r, cnt_r, flags only
    char* zbase = p;
    float* deg_r   = (float*)carve(4 * NN * 4);
    int*   cnt_r   = (int*)carve(4 * NN * 4);
    int*   flags   = (int*)carve(256);
    size_t zspan = (size_t)(p - zbase);
    int*   rank    = (int*)carve(NE * 4);
    int*   repoff  = (int*)carve(4 * NN * 4);
    int*   cnt     = (int*)carve(NN * 4);
    float* logitsC = (float*)carve(MPAD2 * 4);
    int*   offs   = (int*)carve(NN * 4);
    float* dinv   = (float*)carve(NN * 4);
    int*   mtmp   = (int*)carve(NN * 4);
    int*   perm   = (int*)carve(NN * 4);
    int*   bc     = (int*)carve(NN * 4);
    int*   bcnt   = (int*)carve(NBLK * 4);
    int*   bmsk   = (int*)carve(NBLK * 4);
    int*   nmp    = (int*)carve(256);
    int*   ssrc   = (int*)carve(NE * 4);
    float* snorm  = (float*)carve(NE * 4);
    float* Axf    = (float*)carve(NN * 5 * 4);
    unsigned short* W2t = (unsigned short*)carve((size_t)KP * KP * 2);
    unsigned short* G   = (unsigned short*)carve((size_t)MPAD2 * KP * 2);

    hipMemsetAsync(zbase, 0, zspan, stream);
    hipLaunchKernelGGL(deg_cnt_kernel,     dim3(625),       dim3(256), 0, stream, ei, ew, mask, deg_r, cnt_r, flags, rank);
    hipLaunchKernelGGL(partial_w2t_kernel, dim3(NBLK+1024), dim3(256), 0, stream, cnt_r, deg_r, mask, flags, mtmp, dinv, cnt, repoff, bcnt, bmsk, W2, W2t, logitsC);
    hipLaunchKernelGGL(apply_kernel,       dim3(NBLK),      dim3(256), 0, stream, cnt, mtmp, bcnt, bmsk, batch, offs, perm, bc, nmp, out);
    hipLaunchKernelGGL(scatter_kernel,     dim3(625),       dim3(256), 0, stream, ei, ew, dinv, offs, repoff, rank, ssrc, snorm);
    hipLaunchKernelGGL(axf_kernel,         dim3(79),        dim3(256), 0, stream, x, ssrc, snorm, offs, cnt, dinv, Axf);
    hipLaunchKernelGGL(aggW1_kernel,       dim3(MPAD2/8),   dim3(256), 0, stream, Axf, W1, b1, ssrc, snorm, offs, cnt, dinv, perm, nmp, G);
    hipLaunchKernelGGL(gemm_kernel,        dim3(MPAD2/64*8),dim3(256), 0, stream, G, W2t, b2, Wf, nmp, logitsC);
    hipLaunchKernelGGL(softmax_kernel,     dim3(NG),        dim3(256), 0, stream, logitsC, perm, bc, nmp, out);
}